// Round 1
// baseline (85.573 us; speedup 1.0000x reference)
//
#include <hip/hip_runtime.h>
#include <stdint.h>

// ---------------- ws layout (u32 indices) ----------------
#define W1P   0      // 90    [c*5+ky], 5 bits (kx), bit=1 <=> w<0
#define W2P   96     // 1200  [o*25 + ky*5+kx], 18 bits (c)
#define W3P   1296   // 6000  [w*120 + o], w = pos*2 + h, 32 bits (c = h*32+j, c<48)
#define FW1P  7296   // 1008  [wi*252 + o], bits j: col = wi*32+j (<120)
#define FW2P  8304   // 80    [wi*10 + o],  bits j: col = wi*32+j (<252)
#define CONST 8384   // 1344 floats
#define NPACK 9728

// const sub-offsets (float index inside CONST region)
#define B1 0
#define S1 18
#define T1 36
#define B2 54
#define S2 102
#define T2 150
#define B3 198
#define S3 318
#define T3 438
#define B4 558
#define S4 810
#define T4 1062
#define B5 1314
#define S5 1324
#define T5 1334

__global__ __launch_bounds__(256) void pack_kernel(
    const float* __restrict__ w1, const float* __restrict__ w2, const float* __restrict__ w3,
    const float* __restrict__ fw1, const float* __restrict__ fw2,
    const float* __restrict__ cb1, const float* __restrict__ g1, const float* __restrict__ be1,
    const float* __restrict__ m1, const float* __restrict__ v1,
    const float* __restrict__ cb2, const float* __restrict__ g2, const float* __restrict__ be2,
    const float* __restrict__ m2, const float* __restrict__ v2,
    const float* __restrict__ cb3, const float* __restrict__ g3, const float* __restrict__ be3,
    const float* __restrict__ m3, const float* __restrict__ v3,
    const float* __restrict__ fb1, const float* __restrict__ g4, const float* __restrict__ be4,
    const float* __restrict__ m4, const float* __restrict__ v4,
    const float* __restrict__ fb2, const float* __restrict__ g5, const float* __restrict__ be5,
    const float* __restrict__ m5, const float* __restrict__ v5,
    uint32_t* __restrict__ wsu)
{
  const int tid = blockIdx.x * 256 + threadIdx.x;
  if (tid >= NPACK) return;

  if (tid < 90) {                       // w1 bits
    int c = tid / 5, ky = tid % 5;
    uint32_t b = 0;
    for (int kx = 0; kx < 5; ++kx)
      if (w1[c*25 + ky*5 + kx] < 0.0f) b |= 1u << kx;
    wsu[W1P + tid] = b;
  } else if (tid < 96) {                // pad
    wsu[tid] = 0;
  } else if (tid < 1296) {              // w2 bits (18 channels per word)
    int i = tid - 96;
    int o = i / 25, k = i % 25;
    uint32_t b = 0;
    for (int c = 0; c < 18; ++c)
      if (w2[(o*18 + c)*25 + k] < 0.0f) b |= 1u << c;
    wsu[tid] = b;
  } else if (tid < 7296) {              // w3 bits, transposed [w][o]
    int i = tid - 1296;
    int w = i / 120, o = i % 120;
    int pos = w >> 1, h = w & 1;
    uint32_t b = 0;
    for (int j = 0; j < 32; ++j) {
      int c = h*32 + j;
      if (c < 48 && w3[(o*48 + c)*25 + pos] < 0.0f) b |= 1u << j;
    }
    wsu[tid] = b;
  } else if (tid < 8304) {              // fw1 bits, transposed [wi][o]
    int i = tid - 7296;
    int wi = i / 252, o = i % 252;
    uint32_t b = 0;
    for (int j = 0; j < 32; ++j) {
      int col = wi*32 + j;
      if (col < 120 && fw1[o*120 + col] < 0.0f) b |= 1u << j;
    }
    wsu[tid] = b;
  } else if (tid < 8384) {              // fw2 bits, transposed [wi][o]
    int i = tid - 8304;
    int wi = i / 10, o = i % 10;
    uint32_t b = 0;
    for (int j = 0; j < 32; ++j) {
      int col = wi*32 + j;
      if (col < 252 && fw2[o*252 + col] < 0.0f) b |= 1u << j;
    }
    wsu[tid] = b;
  } else {                              // BN constants (cb, s, t) per stage
    int j = tid - CONST;                // 0..1343
    const float *CB, *G, *BE, *M, *V;
    int n, rel;
    if (j < 54)        { n = 18;  rel = j;        CB = cb1; G = g1; BE = be1; M = m1; V = v1; }
    else if (j < 198)  { n = 48;  rel = j - 54;   CB = cb2; G = g2; BE = be2; M = m2; V = v2; }
    else if (j < 558)  { n = 120; rel = j - 198;  CB = cb3; G = g3; BE = be3; M = m3; V = v3; }
    else if (j < 1314) { n = 252; rel = j - 558;  CB = fb1; G = g4; BE = be4; M = m4; V = v4; }
    else               { n = 10;  rel = j - 1314; CB = fb2; G = g5; BE = be5; M = m5; V = v5; }
    int kind = rel / n, c = rel % n;
    float s = __fdiv_rn(G[c], __fsqrt_rn(__fadd_rn(V[c], 1e-5f)));
    float outv;
    if (kind == 0)      outv = CB[c];
    else if (kind == 1) outv = s;
    else                outv = __fsub_rn(BE[c], __fmul_rn(M[c], s));
    wsu[tid] = __float_as_uint(outv);
  }
}

__global__ __launch_bounds__(256) void lenet_main(
    const float* __restrict__ x, const uint32_t* __restrict__ wsu,
    float* __restrict__ out)
{
  __shared__ uint32_t sW[1296];   // W1P (90) + pad + W2P (1200)
  __shared__ float    sC[1344];   // BN constants
  __shared__ uint32_t xnz[32], xng[32];
  __shared__ uint32_t h1w[196];   // per (y,x) of 14x14: 18 channel sign bits
  __shared__ uint32_t h2w[50];    // per (y,x) of 5x5: 48 channel bits in 2 words
  __shared__ uint32_t h3b[4];     // 120 bits
  __shared__ uint32_t h4b[8];     // 252 bits
  __shared__ float    slog[10];
  __shared__ int      zflag;

  const int t = threadIdx.x;
  const int img = blockIdx.x;

  for (int i = t; i < 1296; i += 256) sW[i] = wsu[i];
  for (int i = t; i < 1344; i += 256) sC[i] = __uint_as_float(wsu[CONST + i]);
  if (t < 196) h1w[t] = 0;
  if (t < 50)  h2w[t] = 0;
  if (t < 4)   h3b[t] = 0;
  if (t < 8)   h4b[t] = 0;
  if (t == 0)  zflag = 0;
  __syncthreads();

  // ---- pack input image (32x32) into per-row bitmasks via wave ballots ----
  {
    const float* xim = x + (size_t)img * 1024;
    const int lane = t & 63, wv = t >> 6;
    for (int i = 0; i < 4; ++i) {
      float v = xim[i*256 + t];
      unsigned long long mnz = __ballot(v != 0.0f);
      unsigned long long mng = __ballot(v < 0.0f);
      if (lane == 0) {
        int chunk = i*4 + wv;            // 64 px = 2 rows per chunk
        xnz[chunk*2]   = (uint32_t)mnz;
        xnz[chunk*2+1] = (uint32_t)(mnz >> 32);
        xng[chunk*2]   = (uint32_t)mng;
        xng[chunk*2+1] = (uint32_t)(mng >> 32);
        if (mnz != 0xFFFFFFFFFFFFFFFFull) atomicOr(&zflag, 1);
      }
    }
  }
  __syncthreads();

  // ---- stage 1: conv1 (1->18, 5x5) + cb1, maxpool2, bn sign ----
  const bool zer = (zflag != 0);
  if (t < 196) {
    const int p = t, py = p / 14, px = p % 14;
    const int y0 = py*2, x0 = px*2;
    uint32_t sng[6][2], snz[6][2];
    for (int r = 0; r < 6; ++r) {
      uint32_t rng = xng[y0 + r], rnz = xnz[y0 + r];
      sng[r][0] = (rng >> x0) & 31u;  sng[r][1] = (rng >> (x0+1)) & 31u;
      snz[r][0] = (rnz >> x0) & 31u;  snz[r][1] = (rnz >> (x0+1)) & 31u;
    }
    for (int c = 0; c < 18; ++c) {
      const uint32_t wt0 = sW[c*5+0], wt1 = sW[c*5+1], wt2 = sW[c*5+2],
                     wt3 = sW[c*5+3], wt4 = sW[c*5+4];
      int best = -1000;
      for (int dy = 0; dy < 2; ++dy)
        for (int dx = 0; dx < 2; ++dx) {
          int conv;
          if (!zer) {
            int ng = __popc(sng[dy+0][dx] ^ wt0) + __popc(sng[dy+1][dx] ^ wt1)
                   + __popc(sng[dy+2][dx] ^ wt2) + __popc(sng[dy+3][dx] ^ wt3)
                   + __popc(sng[dy+4][dx] ^ wt4);
            conv = 25 - 2*ng;
          } else {                      // exact-zero-aware path (rare)
            int cnt = 0, ng = 0;
            const uint32_t wts[5] = {wt0, wt1, wt2, wt3, wt4};
            for (int ky = 0; ky < 5; ++ky) {
              uint32_t nz = snz[dy+ky][dx];
              cnt += __popc(nz);
              ng  += __popc((sng[dy+ky][dx] ^ wts[ky]) & nz);
            }
            conv = cnt - 2*ng;
          }
          best = best > conv ? best : conv;
        }
      float v = __fadd_rn((float)best, sC[B1 + c]);
      v = __fmul_rn(v, sC[S1 + c]);
      v = __fadd_rn(v, sC[T1 + c]);
      if (v < 0.0f) atomicOr(&h1w[p], 1u << c);
    }
  }
  __syncthreads();

  // ---- stage 2: conv2 (18->48, 5x5) + cb2, maxpool2, bn sign ----
  if (t < 250) {
    const int p = t / 10, og = t % 10;
    const int py = p / 5, px = p % 5;
    const int y0 = py*2, x0 = px*2;
    uint32_t win[6][6];
    for (int r = 0; r < 6; ++r)
      for (int c = 0; c < 6; ++c)
        win[r][c] = h1w[(y0 + r)*14 + (x0 + c)];
    for (int o = og; o < 48; o += 10) {
      uint32_t wt[25];
      for (int k = 0; k < 25; ++k) wt[k] = sW[96 + o*25 + k];
      int best = -100000;
      for (int dy = 0; dy < 2; ++dy)
        for (int dx = 0; dx < 2; ++dx) {
          int ng = 0;
          for (int ky = 0; ky < 5; ++ky)
            for (int kx = 0; kx < 5; ++kx)
              ng += __popc(win[dy+ky][dx+kx] ^ wt[ky*5+kx]);
          int conv = 450 - 2*ng;
          best = best > conv ? best : conv;
        }
      float v = __fadd_rn((float)best, sC[B2 + o]);
      v = __fmul_rn(v, sC[S2 + o]);
      v = __fadd_rn(v, sC[T2 + o]);
      if (v < 0.0f) atomicOr(&h2w[p*2 + (o >> 5)], 1u << (o & 31));
    }
  }
  __syncthreads();

  // ---- stage 3: conv3 (48->120, 5x5 on 5x5 -> 1x1) + cb3, bn sign ----
  if (t < 120) {
    const int o = t;
    int ng = 0;
    for (int w = 0; w < 50; ++w)
      ng += __popc(h2w[w] ^ wsu[W3P + w*120 + o]);   // coalesced over o
    int dot = 1200 - 2*ng;
    float v = __fadd_rn((float)dot, sC[B3 + o]);
    v = __fmul_rn(v, sC[S3 + o]);
    v = __fadd_rn(v, sC[T3 + o]);
    if (v < 0.0f) atomicOr(&h3b[o >> 5], 1u << (o & 31));
  }
  __syncthreads();

  // ---- stage 4: fc1 (120->252) + fb1, bn sign ----
  if (t < 252) {
    const int o = t;
    int ng = 0;
    for (int wi = 0; wi < 4; ++wi)
      ng += __popc(h3b[wi] ^ wsu[FW1P + wi*252 + o]);
    int dot = 120 - 2*ng;
    float v = __fadd_rn((float)dot, sC[B4 + o]);
    v = __fmul_rn(v, sC[S4 + o]);
    v = __fadd_rn(v, sC[T4 + o]);
    if (v < 0.0f) atomicOr(&h4b[o >> 5], 1u << (o & 31));
  }
  __syncthreads();

  // ---- stage 5: fc2 (252->10) + fb2, bn, log_softmax ----
  if (t < 10) {
    int ng = 0;
    for (int wi = 0; wi < 8; ++wi)
      ng += __popc(h4b[wi] ^ wsu[FW2P + wi*10 + t]);
    int dot = 252 - 2*ng;
    float v = __fadd_rn((float)dot, sC[B5 + t]);
    v = __fmul_rn(v, sC[S5 + t]);
    v = __fadd_rn(v, sC[T5 + t]);
    slog[t] = v;
  }
  __syncthreads();
  if (t == 0) {
    float mx = slog[0];
    for (int i = 1; i < 10; ++i) mx = fmaxf(mx, slog[i]);
    float sh[10];
    float s = 0.0f;
    for (int i = 0; i < 10; ++i) {
      sh[i] = __fsub_rn(slog[i], mx);
      s = __fadd_rn(s, expf(sh[i]));
    }
    float ls = logf(s);
    float* op = out + (size_t)img * 10;
    for (int i = 0; i < 10; ++i) op[i] = __fsub_rn(sh[i], ls);
  }
}

extern "C" void kernel_launch(void* const* d_in, const int* in_sizes, int n_in,
                              void* d_out, int out_size, void* d_ws, size_t ws_size,
                              hipStream_t stream)
{
  const float* x   = (const float*)d_in[0];
  const float* w1  = (const float*)d_in[1];
  const float* cb1 = (const float*)d_in[2];
  const float* g1  = (const float*)d_in[3];
  const float* be1 = (const float*)d_in[4];
  const float* m1  = (const float*)d_in[5];
  const float* v1  = (const float*)d_in[6];
  const float* w2  = (const float*)d_in[7];
  const float* cb2 = (const float*)d_in[8];
  const float* g2  = (const float*)d_in[9];
  const float* be2 = (const float*)d_in[10];
  const float* m2  = (const float*)d_in[11];
  const float* v2  = (const float*)d_in[12];
  const float* w3  = (const float*)d_in[13];
  const float* cb3 = (const float*)d_in[14];
  const float* g3  = (const float*)d_in[15];
  const float* be3 = (const float*)d_in[16];
  const float* m3  = (const float*)d_in[17];
  const float* v3  = (const float*)d_in[18];
  const float* fw1 = (const float*)d_in[19];
  const float* fb1 = (const float*)d_in[20];
  const float* g4  = (const float*)d_in[21];
  const float* be4 = (const float*)d_in[22];
  const float* m4  = (const float*)d_in[23];
  const float* v4  = (const float*)d_in[24];
  const float* fw2 = (const float*)d_in[25];
  const float* fb2 = (const float*)d_in[26];
  const float* g5  = (const float*)d_in[27];
  const float* be5 = (const float*)d_in[28];
  const float* m5  = (const float*)d_in[29];
  const float* v5  = (const float*)d_in[30];

  uint32_t* wsu = (uint32_t*)d_ws;
  float* out = (float*)d_out;

  hipLaunchKernelGGL(pack_kernel, dim3(38), dim3(256), 0, stream,
                     w1, w2, w3, fw1, fw2,
                     cb1, g1, be1, m1, v1,
                     cb2, g2, be2, m2, v2,
                     cb3, g3, be3, m3, v3,
                     fb1, g4, be4, m4, v4,
                     fb2, g5, be5, m5, v5,
                     wsu);

  hipLaunchKernelGGL(lenet_main, dim3(4096), dim3(256), 0, stream,
                     x, wsu, out);
}

// Round 2
// 70.166 us; speedup vs baseline: 1.2196x; 1.2196x over previous
//
#include <hip/hip_runtime.h>
#include <stdint.h>

// ---------------- ws layout (u32 indices) ----------------
#define W1P   0      // 18   per channel: wt25 (bits 0..24) | M<<25
#define INV1  18     // 1    bit c = inv_c for stage1
#define W2P   32     // 768  48 o x 16 words: dense 480-bit weights + [15]=M|inv<<9
#define W3P   800    // 6000 [w*120 + o], w = pos*2 + h, bits c = h*32+j (c<48)
#define M3P   6800   // 120  M | inv<<11
#define FW1P  6920   // 1008 [wi*252 + o], bits j: col = wi*32+j (<120)
#define M4P   7928   // 252  M | inv<<7
#define FW2P  8180   // 80   [wi*10 + o], bits j: col = wi*32+j (<252)
#define CFP   8260   // 84 floats: B1[18] S1[18] T1[18] B5[10] S5[10] T5[10]

__device__ inline bool negv(int dot, float B, float S, float T) {
  float v = __fadd_rn((float)dot, B);
  v = __fmul_rn(v, S);
  v = __fadd_rn(v, T);
  return v < 0.0f;
}

// neg-set over m (mismatch count, dot = tot-2m) is a prefix or suffix
// (affine in m). Represent as: neg(m) == ((m >= M) ^ inv).
__device__ inline void scanMT(float B, float S, float T, int tot, int& M, int& inv) {
  bool b0 = negv(tot, B, S, T);     // m = 0
  bool be = negv(-tot, B, S, T);    // m = tot
  if (b0 == be) { M = 0; inv = b0 ? 0 : 1; return; }
  if (!b0) { int m = 1; while (!negv(tot - 2*m, B, S, T)) ++m; M = m; inv = 0; }
  else     { int m = 1; while ( negv(tot - 2*m, B, S, T)) ++m; M = m; inv = 1; }
}

__device__ inline float bnS(float g, float v) {
  return __fdiv_rn(g, __fsqrt_rn(__fadd_rn(v, 1e-5f)));
}
__device__ inline float bnT(float be, float m, float s) {
  return __fsub_rn(be, __fmul_rn(m, s));
}

__global__ __launch_bounds__(256) void pack_kernel(
    const float* __restrict__ w1, const float* __restrict__ w2, const float* __restrict__ w3,
    const float* __restrict__ fw1, const float* __restrict__ fw2,
    const float* __restrict__ cb1, const float* __restrict__ g1, const float* __restrict__ be1,
    const float* __restrict__ m1, const float* __restrict__ v1,
    const float* __restrict__ cb2, const float* __restrict__ g2, const float* __restrict__ be2,
    const float* __restrict__ m2, const float* __restrict__ v2,
    const float* __restrict__ cb3, const float* __restrict__ g3, const float* __restrict__ be3,
    const float* __restrict__ m3, const float* __restrict__ v3,
    const float* __restrict__ fb1, const float* __restrict__ g4, const float* __restrict__ be4,
    const float* __restrict__ m4, const float* __restrict__ v4,
    const float* __restrict__ fb2, const float* __restrict__ g5, const float* __restrict__ be5,
    const float* __restrict__ m5, const float* __restrict__ v5,
    uint32_t* __restrict__ wsu)
{
  const int tid = blockIdx.x * 256 + threadIdx.x;

  if (tid < 18) {                         // w1 packed 25-bit + M
    int c = tid;
    uint32_t wt = 0;
    for (int ky = 0; ky < 5; ++ky)
      for (int kx = 0; kx < 5; ++kx)
        if (w1[c*25 + ky*5 + kx] < 0.0f) wt |= 1u << (ky*5 + kx);
    float S = bnS(g1[c], v1[c]);
    float B = cb1[c];
    float T = bnT(be1[c], m1[c], S);
    int M, iv; scanMT(B, S, T, 25, M, iv);
    wsu[W1P + c] = wt | ((uint32_t)M << 25);
  } else if (tid == 18) {                 // inv mask for stage1
    uint32_t mask = 0;
    for (int c = 0; c < 18; ++c) {
      float S = bnS(g1[c], v1[c]);
      float B = cb1[c];
      float T = bnT(be1[c], m1[c], S);
      int M, iv; scanMT(B, S, T, 25, M, iv);
      if (iv) mask |= 1u << c;
    }
    wsu[INV1] = mask;
  } else if (tid >= 32 && tid < 80) {     // w2 dense pack + M2
    int o = tid - 32;
    uint32_t W[16];
    for (int ky = 0; ky < 5; ++ky) {
      uint32_t mw[5];
      for (int kx = 0; kx < 5; ++kx) {
        uint32_t b = 0;
        for (int c = 0; c < 18; ++c)
          if (w2[(o*18 + c)*25 + ky*5 + kx] < 0.0f) b |= 1u << c;
        mw[kx] = b;
      }
      W[3*ky+0] = mw[0] | (mw[1] << 18);
      W[3*ky+1] = (mw[1] >> 14) | (mw[2] << 4) | (mw[3] << 22);
      W[3*ky+2] = (mw[3] >> 10) | (mw[4] << 8);
    }
    float S = bnS(g2[o], v2[o]);
    float B = cb2[o];
    float T = bnT(be2[o], m2[o], S);
    int M, iv; scanMT(B, S, T, 450, M, iv);
    W[15] = (uint32_t)M | ((uint32_t)iv << 9);
    for (int q = 0; q < 16; ++q) wsu[W2P + o*16 + q] = W[q];
  } else if (tid >= 96 && tid < 6096) {   // w3 bits, transposed [w][o]
    int i = tid - 96;
    int w = i / 120, o = i % 120;
    int pos = w >> 1, h = w & 1;
    uint32_t b = 0;
    for (int j = 0; j < 32; ++j) {
      int c = h*32 + j;
      if (c < 48 && w3[(o*48 + c)*25 + pos] < 0.0f) b |= 1u << j;
    }
    wsu[W3P + i] = b;
  } else if (tid >= 6096 && tid < 6216) { // M3
    int o = tid - 6096;
    float S = bnS(g3[o], v3[o]);
    float B = cb3[o];
    float T = bnT(be3[o], m3[o], S);
    int M, iv; scanMT(B, S, T, 1200, M, iv);
    wsu[M3P + o] = (uint32_t)M | ((uint32_t)iv << 11);
  } else if (tid >= 6216 && tid < 7224) { // fw1 bits, transposed
    int i = tid - 6216;
    int wi = i / 252, o = i % 252;
    uint32_t b = 0;
    for (int j = 0; j < 32; ++j) {
      int col = wi*32 + j;
      if (col < 120 && fw1[o*120 + col] < 0.0f) b |= 1u << j;
    }
    wsu[FW1P + i] = b;
  } else if (tid >= 7224 && tid < 7476) { // M4
    int o = tid - 7224;
    float S = bnS(g4[o], v4[o]);
    float B = fb1[o];
    float T = bnT(be4[o], m4[o], S);
    int M, iv; scanMT(B, S, T, 120, M, iv);
    wsu[M4P + o] = (uint32_t)M | ((uint32_t)iv << 7);
  } else if (tid >= 7476 && tid < 7556) { // fw2 bits, transposed
    int i = tid - 7476;
    int wi = i / 10, o = i % 10;
    uint32_t b = 0;
    for (int j = 0; j < 32; ++j) {
      int col = wi*32 + j;
      if (col < 252 && fw2[o*252 + col] < 0.0f) b |= 1u << j;
    }
    wsu[FW2P + i] = b;
  } else if (tid >= 7556 && tid < 7640) { // CF floats
    int j = tid - 7556;
    float outv;
    if (j < 18) outv = cb1[j];
    else if (j < 36) { int c = j - 18; outv = bnS(g1[c], v1[c]); }
    else if (j < 54) { int c = j - 36; float s = bnS(g1[c], v1[c]); outv = bnT(be1[c], m1[c], s); }
    else if (j < 64) { int c = j - 54; outv = fb2[c]; }
    else if (j < 74) { int c = j - 64; outv = bnS(g5[c], v5[c]); }
    else             { int c = j - 74; float s = bnS(g5[c], v5[c]); outv = bnT(be5[c], m5[c], s); }
    wsu[CFP + j] = __float_as_uint(outv);
  }
}

__global__ __launch_bounds__(256) void lenet_main(
    const float* __restrict__ x, const uint32_t* __restrict__ wsu,
    float* __restrict__ out)
{
  __shared__ uint32_t sW1[18];
  __shared__ uint32_t sInv1;
  __shared__ uint4    sW2[192];      // 48 o x 4 uint4
  __shared__ uint32_t xng[32], xnz[32];
  __shared__ uint32_t h1w[196];      // per 14x14 pixel: 18 channel neg-bits
  __shared__ uint4    sSeg[140];     // [row*10+x]: dense 96-bit row segment (+pad)
  __shared__ uint32_t h2w[50];
  __shared__ uint32_t h3b[4];
  __shared__ uint32_t h4b[8];
  __shared__ float    slog[10];
  __shared__ int      zflag;

  const int t = threadIdx.x;
  const int img = blockIdx.x;

  if (t < 192) sW2[t] = ((const uint4*)(wsu + W2P))[t];
  if (t < 18)  sW1[t] = wsu[W1P + t];
  if (t == 18) sInv1 = wsu[INV1];
  if (t < 50)  h2w[t] = 0;
  if (t < 4)   h3b[t] = 0;
  if (t < 8)   h4b[t] = 0;
  if (t == 19) zflag = 0;
  __syncthreads();

  // ---- pack input image (32x32) into per-row bitmasks via wave ballots ----
  {
    const float* xim = x + (size_t)img * 1024;
    const int lane = t & 63, wv = t >> 6;
    for (int i = 0; i < 4; ++i) {
      float v = xim[i*256 + t];
      unsigned long long mnz = __ballot(v != 0.0f);
      unsigned long long mng = __ballot(v < 0.0f);
      if (lane == 0) {
        int chunk = i*4 + wv;            // 64 px = 2 rows per chunk
        xnz[chunk*2]   = (uint32_t)mnz;
        xnz[chunk*2+1] = (uint32_t)(mnz >> 32);
        xng[chunk*2]   = (uint32_t)mng;
        xng[chunk*2+1] = (uint32_t)(mng >> 32);
        if (mnz != 0xFFFFFFFFFFFFFFFFull) atomicOr(&zflag, 1);
      }
    }
  }
  __syncthreads();

  // ---- stage 1: conv1 via packed 25-bit windows + int thresholds ----
  const bool zer = (zflag != 0);
  if (t < 196) {
    const int py = t / 14, px = t % 14;
    const int y0 = 2*py, x0 = 2*px;
    uint32_t hm = 0;
    if (!zer) {
      uint32_t a[6];
      #pragma unroll
      for (int r = 0; r < 6; ++r) a[r] = xng[y0 + r] >> x0;
      uint32_t w00 = 0, w01 = 0, w10 = 0, w11 = 0;
      #pragma unroll
      for (int k = 0; k < 5; ++k) {
        w00 |= (a[k]   & 31u) << (5*k);
        w01 |= ((a[k] >> 1) & 31u) << (5*k);
        w10 |= (a[k+1] & 31u) << (5*k);
        w11 |= ((a[k+1] >> 1) & 31u) << (5*k);
      }
      const uint32_t iv1 = sInv1;
      #pragma unroll
      for (int c = 0; c < 18; ++c) {
        uint32_t wd = sW1[c];
        uint32_t wt = wd & 0x1FFFFFFu;
        int M = (int)(wd >> 25);
        int m0 = __popc(w00 ^ wt), mA = __popc(w01 ^ wt);
        int m2 = __popc(w10 ^ wt), m3 = __popc(w11 ^ wt);
        int mn = min(min(m0, mA), min(m2, m3));
        if (mn >= M) hm |= 1u << c;
      }
      hm ^= iv1;
    } else {                             // exact-zero-aware float path (rare)
      uint32_t an[6], az[6];
      #pragma unroll
      for (int r = 0; r < 6; ++r) { an[r] = xng[y0+r] >> x0; az[r] = xnz[y0+r] >> x0; }
      for (int c = 0; c < 18; ++c) {
        uint32_t wt = sW1[c] & 0x1FFFFFFu;
        float B = __uint_as_float(wsu[CFP + c]);
        float S = __uint_as_float(wsu[CFP + 18 + c]);
        float T = __uint_as_float(wsu[CFP + 36 + c]);
        int best = -1000;
        for (int dy = 0; dy < 2; ++dy)
          for (int dx = 0; dx < 2; ++dx) {
            int cnt = 0, ng = 0;
            for (int k = 0; k < 5; ++k) {
              uint32_t nz = (az[dy+k] >> dx) & 31u;
              uint32_t sg = (an[dy+k] >> dx) & 31u;
              uint32_t wr = (wt >> (5*k)) & 31u;
              cnt += __popc(nz);
              ng  += __popc((sg ^ wr) & nz);
            }
            int conv = cnt - 2*ng;
            best = best > conv ? best : conv;
          }
        if (negv(best, B, S, T)) hm |= 1u << c;
      }
    }
    h1w[t] = hm;
  }
  __syncthreads();

  // ---- build dense 96-bit im2col row segments: seg[row][x], x=0..9 ----
  if (t < 140) {
    const int row = t / 10, xx = t % 10;
    const uint32_t* hp = &h1w[row*14 + xx];
    uint32_t m0 = hp[0], m1 = hp[1], m2 = hp[2], m3 = hp[3], m4 = hp[4];
    uint4 sg;
    sg.x = m0 | (m1 << 18);
    sg.y = (m1 >> 14) | (m2 << 4) | (m3 << 22);
    sg.z = (m3 >> 10) | (m4 << 8);
    sg.w = 0;
    sSeg[t] = sg;
  }
  __syncthreads();

  // ---- stage 2: conv2 dense popcount + int thresholds ----
  if (t < 250) {
    const int p = t / 10, og = t % 10;
    const int py = p / 5, px = p % 5;
    const int sb = (2*py)*10 + 2*px;
    uint4 sg[6][2];
    #pragma unroll
    for (int r = 0; r < 6; ++r) {
      sg[r][0] = sSeg[sb + r*10];
      sg[r][1] = sSeg[sb + r*10 + 1];
    }
    uint32_t lo = 0, hi = 0;
    #pragma unroll
    for (int j = 0; j < 5; ++j) {
      int o = og + 10*j;
      if (o < 48) {
        uint4 W4[4];
        W4[0] = sW2[o*4+0]; W4[1] = sW2[o*4+1]; W4[2] = sW2[o*4+2]; W4[3] = sW2[o*4+3];
        const uint32_t* W = (const uint32_t*)W4;
        int m00 = 0, m01 = 0, m10 = 0, m11 = 0;
        #pragma unroll
        for (int k = 0; k < 5; ++k) {
          uint32_t a = W[3*k], b = W[3*k+1], c = W[3*k+2];
          m00 += __popc(sg[k][0].x ^ a) + __popc(sg[k][0].y ^ b) + __popc(sg[k][0].z ^ c);
          m01 += __popc(sg[k][1].x ^ a) + __popc(sg[k][1].y ^ b) + __popc(sg[k][1].z ^ c);
          m10 += __popc(sg[k+1][0].x ^ a) + __popc(sg[k+1][0].y ^ b) + __popc(sg[k+1][0].z ^ c);
          m11 += __popc(sg[k+1][1].x ^ a) + __popc(sg[k+1][1].y ^ b) + __popc(sg[k+1][1].z ^ c);
        }
        int mn = min(min(m00, m01), min(m10, m11));
        uint32_t mw = W[15];
        int M = (int)(mw & 511u), iv = (int)((mw >> 9) & 1u);
        int bit = ((mn >= M) ? 1 : 0) ^ iv;
        if (bit) { if (o < 32) lo |= 1u << o; else hi |= 1u << (o - 32); }
      }
    }
    if (lo) atomicOr(&h2w[p*2], lo);
    if (hi) atomicOr(&h2w[p*2+1], hi);
  }
  __syncthreads();

  // ---- stage 3: conv3 (48->120) + int thresholds ----
  if (t < 120) {
    const int o = t;
    int mm = 0;
    #pragma unroll 10
    for (int w = 0; w < 50; ++w)
      mm += __popc(h2w[w] ^ wsu[W3P + w*120 + o]);
    uint32_t mw = wsu[M3P + o];
    int M = (int)(mw & 2047u), iv = (int)(mw >> 11);
    int bit = ((mm >= M) ? 1 : 0) ^ iv;
    if (bit) atomicOr(&h3b[o >> 5], 1u << (o & 31));
  }
  __syncthreads();

  // ---- stage 4: fc1 (120->252) + int thresholds ----
  if (t < 252) {
    const int o = t;
    int mm = 0;
    #pragma unroll
    for (int wi = 0; wi < 4; ++wi)
      mm += __popc(h3b[wi] ^ wsu[FW1P + wi*252 + o]);
    uint32_t mw = wsu[M4P + o];
    int M = (int)(mw & 127u), iv = (int)(mw >> 7);
    int bit = ((mm >= M) ? 1 : 0) ^ iv;
    if (bit) atomicOr(&h4b[o >> 5], 1u << (o & 31));
  }
  __syncthreads();

  // ---- stage 5: fc2 (252->10) + bn, log_softmax ----
  if (t < 10) {
    int mm = 0;
    #pragma unroll
    for (int wi = 0; wi < 8; ++wi)
      mm += __popc(h4b[wi] ^ wsu[FW2P + wi*10 + t]);
    int dot = 252 - 2*mm;
    float B = __uint_as_float(wsu[CFP + 54 + t]);
    float S = __uint_as_float(wsu[CFP + 64 + t]);
    float T = __uint_as_float(wsu[CFP + 74 + t]);
    float v = __fadd_rn((float)dot, B);
    v = __fmul_rn(v, S);
    v = __fadd_rn(v, T);
    slog[t] = v;
  }
  __syncthreads();
  if (t == 0) {
    float mx = slog[0];
    for (int i = 1; i < 10; ++i) mx = fmaxf(mx, slog[i]);
    float sh[10];
    float s = 0.0f;
    for (int i = 0; i < 10; ++i) {
      sh[i] = __fsub_rn(slog[i], mx);
      s = __fadd_rn(s, expf(sh[i]));
    }
    float ls = logf(s);
    float* op = out + (size_t)img * 10;
    for (int i = 0; i < 10; ++i) op[i] = __fsub_rn(sh[i], ls);
  }
}

extern "C" void kernel_launch(void* const* d_in, const int* in_sizes, int n_in,
                              void* d_out, int out_size, void* d_ws, size_t ws_size,
                              hipStream_t stream)
{
  const float* x   = (const float*)d_in[0];
  const float* w1  = (const float*)d_in[1];
  const float* cb1 = (const float*)d_in[2];
  const float* g1  = (const float*)d_in[3];
  const float* be1 = (const float*)d_in[4];
  const float* m1  = (const float*)d_in[5];
  const float* v1  = (const float*)d_in[6];
  const float* w2  = (const float*)d_in[7];
  const float* cb2 = (const float*)d_in[8];
  const float* g2  = (const float*)d_in[9];
  const float* be2 = (const float*)d_in[10];
  const float* m2  = (const float*)d_in[11];
  const float* v2  = (const float*)d_in[12];
  const float* w3  = (const float*)d_in[13];
  const float* cb3 = (const float*)d_in[14];
  const float* g3  = (const float*)d_in[15];
  const float* be3 = (const float*)d_in[16];
  const float* m3  = (const float*)d_in[17];
  const float* v3  = (const float*)d_in[18];
  const float* fw1 = (const float*)d_in[19];
  const float* fb1 = (const float*)d_in[20];
  const float* g4  = (const float*)d_in[21];
  const float* be4 = (const float*)d_in[22];
  const float* m4  = (const float*)d_in[23];
  const float* v4  = (const float*)d_in[24];
  const float* fw2 = (const float*)d_in[25];
  const float* fb2 = (const float*)d_in[26];
  const float* g5  = (const float*)d_in[27];
  const float* be5 = (const float*)d_in[28];
  const float* m5  = (const float*)d_in[29];
  const float* v5  = (const float*)d_in[30];

  uint32_t* wsu = (uint32_t*)d_ws;
  float* out = (float*)d_out;

  hipLaunchKernelGGL(pack_kernel, dim3(30), dim3(256), 0, stream,
                     w1, w2, w3, fw1, fw2,
                     cb1, g1, be1, m1, v1,
                     cb2, g2, be2, m2, v2,
                     cb3, g3, be3, m3, v3,
                     fb1, g4, be4, m4, v4,
                     fb2, g5, be5, m5, v5,
                     wsu);

  hipLaunchKernelGGL(lenet_main, dim3(4096), dim3(256), 0, stream,
                     x, wsu, out);
}

// Round 3
// 69.860 us; speedup vs baseline: 1.2249x; 1.0044x over previous
//
#include <hip/hip_runtime.h>
#include <stdint.h>

// ---------------- ws layout (u32 indices) ----------------
#define W1P   0      // 18   per channel: wt25 (bits 0..24) | M<<25
#define INV1  18     // 1    bit c = inv_c for stage1
#define W2P   32     // 768  48 o x 16 words: dense 480-bit weights + [15]=M|inv<<9
#define W3P   800    // 6000 [w*120 + o], w = pos*2 + h, bit j = ch c = h*24+j (j<24)
#define M3P   6800   // 120  M | inv<<11
#define FW1P  6920   // 1008 [wi*252 + o], bits j: col = wi*32+j (<120)
#define M4P   7928   // 252  M | inv<<7
#define FW2P  8180   // 80   [wi*10 + o], bits j: col = wi*32+j (<252)
#define CFP   8260   // 84 floats: B1[18] S1[18] T1[18] B5[10] S5[10] T5[10]

__device__ inline bool negv(int dot, float B, float S, float T) {
  float v = __fadd_rn((float)dot, B);
  v = __fmul_rn(v, S);
  v = __fadd_rn(v, T);
  return v < 0.0f;
}

// neg-set over m (mismatch count, dot = tot-2m) is a prefix or suffix
// (affine in m). Represent as: neg(m) == ((m >= M) ^ inv).
__device__ inline void scanMT(float B, float S, float T, int tot, int& M, int& inv) {
  bool b0 = negv(tot, B, S, T);     // m = 0
  bool be = negv(-tot, B, S, T);    // m = tot
  if (b0 == be) { M = 0; inv = b0 ? 0 : 1; return; }
  if (!b0) { int m = 1; while (!negv(tot - 2*m, B, S, T)) ++m; M = m; inv = 0; }
  else     { int m = 1; while ( negv(tot - 2*m, B, S, T)) ++m; M = m; inv = 1; }
}

__device__ inline float bnS(float g, float v) {
  return __fdiv_rn(g, __fsqrt_rn(__fadd_rn(v, 1e-5f)));
}
__device__ inline float bnT(float be, float m, float s) {
  return __fsub_rn(be, __fmul_rn(m, s));
}

__global__ __launch_bounds__(256) void pack_kernel(
    const float* __restrict__ w1, const float* __restrict__ w2, const float* __restrict__ w3,
    const float* __restrict__ fw1, const float* __restrict__ fw2,
    const float* __restrict__ cb1, const float* __restrict__ g1, const float* __restrict__ be1,
    const float* __restrict__ m1, const float* __restrict__ v1,
    const float* __restrict__ cb2, const float* __restrict__ g2, const float* __restrict__ be2,
    const float* __restrict__ m2, const float* __restrict__ v2,
    const float* __restrict__ cb3, const float* __restrict__ g3, const float* __restrict__ be3,
    const float* __restrict__ m3, const float* __restrict__ v3,
    const float* __restrict__ fb1, const float* __restrict__ g4, const float* __restrict__ be4,
    const float* __restrict__ m4, const float* __restrict__ v4,
    const float* __restrict__ fb2, const float* __restrict__ g5, const float* __restrict__ be5,
    const float* __restrict__ m5, const float* __restrict__ v5,
    uint32_t* __restrict__ wsu)
{
  const int tid = blockIdx.x * 256 + threadIdx.x;

  if (tid < 18) {                         // w1 packed 25-bit + M
    int c = tid;
    uint32_t wt = 0;
    for (int ky = 0; ky < 5; ++ky)
      for (int kx = 0; kx < 5; ++kx)
        if (w1[c*25 + ky*5 + kx] < 0.0f) wt |= 1u << (ky*5 + kx);
    float S = bnS(g1[c], v1[c]);
    float B = cb1[c];
    float T = bnT(be1[c], m1[c], S);
    int M, iv; scanMT(B, S, T, 25, M, iv);
    wsu[W1P + c] = wt | ((uint32_t)M << 25);
  } else if (tid == 18) {                 // inv mask for stage1
    uint32_t mask = 0;
    for (int c = 0; c < 18; ++c) {
      float S = bnS(g1[c], v1[c]);
      float B = cb1[c];
      float T = bnT(be1[c], m1[c], S);
      int M, iv; scanMT(B, S, T, 25, M, iv);
      if (iv) mask |= 1u << c;
    }
    wsu[INV1] = mask;
  } else if (tid >= 32 && tid < 80) {     // w2 dense pack + M2
    int o = tid - 32;
    uint32_t W[16];
    for (int ky = 0; ky < 5; ++ky) {
      uint32_t mw[5];
      for (int kx = 0; kx < 5; ++kx) {
        uint32_t b = 0;
        for (int c = 0; c < 18; ++c)
          if (w2[(o*18 + c)*25 + ky*5 + kx] < 0.0f) b |= 1u << c;
        mw[kx] = b;
      }
      W[3*ky+0] = mw[0] | (mw[1] << 18);
      W[3*ky+1] = (mw[1] >> 14) | (mw[2] << 4) | (mw[3] << 22);
      W[3*ky+2] = (mw[3] >> 10) | (mw[4] << 8);
    }
    float S = bnS(g2[o], v2[o]);
    float B = cb2[o];
    float T = bnT(be2[o], m2[o], S);
    int M, iv; scanMT(B, S, T, 450, M, iv);
    W[15] = (uint32_t)M | ((uint32_t)iv << 9);
    for (int q = 0; q < 16; ++q) wsu[W2P + o*16 + q] = W[q];
  } else if (tid >= 96 && tid < 6096) {   // w3 bits, transposed [w][o], 24ch/word
    int i = tid - 96;
    int w = i / 120, o = i % 120;
    int pos = w >> 1, h = w & 1;
    uint32_t b = 0;
    for (int j = 0; j < 24; ++j) {
      int c = h*24 + j;
      if (w3[(o*48 + c)*25 + pos] < 0.0f) b |= 1u << j;
    }
    wsu[W3P + i] = b;
  } else if (tid >= 6096 && tid < 6216) { // M3
    int o = tid - 6096;
    float S = bnS(g3[o], v3[o]);
    float B = cb3[o];
    float T = bnT(be3[o], m3[o], S);
    int M, iv; scanMT(B, S, T, 1200, M, iv);
    wsu[M3P + o] = (uint32_t)M | ((uint32_t)iv << 11);
  } else if (tid >= 6216 && tid < 7224) { // fw1 bits, transposed
    int i = tid - 6216;
    int wi = i / 252, o = i % 252;
    uint32_t b = 0;
    for (int j = 0; j < 32; ++j) {
      int col = wi*32 + j;
      if (col < 120 && fw1[o*120 + col] < 0.0f) b |= 1u << j;
    }
    wsu[FW1P + i] = b;
  } else if (tid >= 7224 && tid < 7476) { // M4
    int o = tid - 7224;
    float S = bnS(g4[o], v4[o]);
    float B = fb1[o];
    float T = bnT(be4[o], m4[o], S);
    int M, iv; scanMT(B, S, T, 120, M, iv);
    wsu[M4P + o] = (uint32_t)M | ((uint32_t)iv << 7);
  } else if (tid >= 7476 && tid < 7556) { // fw2 bits, transposed
    int i = tid - 7476;
    int wi = i / 10, o = i % 10;
    uint32_t b = 0;
    for (int j = 0; j < 32; ++j) {
      int col = wi*32 + j;
      if (col < 252 && fw2[o*252 + col] < 0.0f) b |= 1u << j;
    }
    wsu[FW2P + i] = b;
  } else if (tid >= 7556 && tid < 7640) { // CF floats
    int j = tid - 7556;
    float outv;
    if (j < 18) outv = cb1[j];
    else if (j < 36) { int c = j - 18; outv = bnS(g1[c], v1[c]); }
    else if (j < 54) { int c = j - 36; float s = bnS(g1[c], v1[c]); outv = bnT(be1[c], m1[c], s); }
    else if (j < 64) { int c = j - 54; outv = fb2[c]; }
    else if (j < 74) { int c = j - 64; outv = bnS(g5[c], v5[c]); }
    else             { int c = j - 74; float s = bnS(g5[c], v5[c]); outv = bnT(be5[c], m5[c], s); }
    wsu[CFP + j] = __float_as_uint(outv);
  }
}

// per-image LDS region (u32 words):
//   0: xng[32]   32: xnz[32]   64: h1w[196]   260: seg[140] uint4   820: h2w[50]
#define WPI 884

#define ROWM(sr, wa, wb, wc) (__popc((sr).x^(wa)) + __popc((sr).y^(wb)) + __popc((sr).z^(wc)))

__global__ __launch_bounds__(256) void lenet_main(
    const float* __restrict__ x, const uint32_t* __restrict__ wsu,
    float* __restrict__ out)
{
  __shared__ uint32_t sW1[19];
  __shared__ uint4    sW2[192];
  __shared__ __align__(16) uint32_t sImg[4 * WPI];

  const int t = threadIdx.x;
  const int lane = t & 63, wid = t >> 6;
  const int img = blockIdx.x * 4 + wid;

  if (t < 192) sW2[t] = ((const uint4*)(wsu + W2P))[t];
  if (t < 19)  sW1[t] = wsu[W1P + t];
  __syncthreads();          // the ONLY block-wide barrier

  uint32_t* R   = sImg + wid * WPI;
  uint32_t* xng = R;
  uint32_t* xnz = R + 32;
  uint32_t* h1w = R + 64;
  uint4*    seg = (uint4*)(R + 260);
  uint32_t* h2w = R + 820;

  // ---- input pack: lane -> (row = lane>>1, half = lane&1), 16 px each ----
  bool allnz;
  {
    const float* xim = x + (size_t)img * 1024;
    const int row = lane >> 1, half = lane & 1;
    const float4* src = (const float4*)(xim + row*32 + half*16);
    uint32_t ng = 0, nz = 0;
    #pragma unroll
    for (int q = 0; q < 4; ++q) {
      float4 f = src[q];
      uint32_t u0 = __float_as_uint(f.x), u1 = __float_as_uint(f.y),
               u2 = __float_as_uint(f.z), u3 = __float_as_uint(f.w);
      const int j = q*4;
      ng |= ((u0>>31)<<j) | ((u1>>31)<<(j+1)) | ((u2>>31)<<(j+2)) | ((u3>>31)<<(j+3));
      nz |= ((uint32_t)((u0<<1)!=0u)<<j) | ((uint32_t)((u1<<1)!=0u)<<(j+1))
          | ((uint32_t)((u2<<1)!=0u)<<(j+2)) | ((uint32_t)((u3<<1)!=0u)<<(j+3));
    }
    uint32_t ong = __shfl_xor(ng, 1);
    uint32_t onz = __shfl_xor(nz, 1);
    if (half == 0) {
      xng[row] = ng | (ong << 16);
      xnz[row] = nz | (onz << 16);
    }
    allnz = (__all(nz == 0xFFFFu) != 0);
  }
  __threadfence_block();
  const bool zer = !allnz;    // wave-uniform

  // ---- stage 1: conv1 + pool + int-threshold sign ----
  if (!zer) {
    const uint32_t iv1 = sW1[18];
    for (int p = lane; p < 196; p += 64) {
      const int py = p / 14, px = p - py*14;
      const int x0 = 2*px;
      const uint32_t a0 = xng[2*py+0] >> x0, a1 = xng[2*py+1] >> x0,
                     a2 = xng[2*py+2] >> x0, a3 = xng[2*py+3] >> x0,
                     a4 = xng[2*py+4] >> x0, a5 = xng[2*py+5] >> x0;
      const uint32_t w00 = (a0&31u) | ((a1&31u)<<5) | ((a2&31u)<<10) | ((a3&31u)<<15) | ((a4&31u)<<20);
      const uint32_t w01 = ((a0>>1)&31u) | (((a1>>1)&31u)<<5) | (((a2>>1)&31u)<<10) | (((a3>>1)&31u)<<15) | (((a4>>1)&31u)<<20);
      const uint32_t w10 = (a1&31u) | ((a2&31u)<<5) | ((a3&31u)<<10) | ((a4&31u)<<15) | ((a5&31u)<<20);
      const uint32_t w11 = ((a1>>1)&31u) | (((a2>>1)&31u)<<5) | (((a3>>1)&31u)<<10) | (((a4>>1)&31u)<<15) | (((a5>>1)&31u)<<20);
      uint32_t hm = 0;
      #pragma unroll
      for (int c = 0; c < 18; ++c) {
        const uint32_t wd = sW1[c];
        const uint32_t wt = wd & 0x1FFFFFFu;
        const int M = (int)(wd >> 25);
        const int mn = min(min(__popc(w00^wt), __popc(w01^wt)),
                           min(__popc(w10^wt), __popc(w11^wt)));
        hm |= (mn >= M) ? (1u << c) : 0u;
      }
      h1w[p] = hm ^ iv1;
    }
  } else {                                  // exact-zero-aware float path (rare)
    for (int p = lane; p < 196; p += 64) {
      const int py = p / 14, px = p - py*14;
      const int x0 = 2*px;
      uint32_t an[6], az[6];
      #pragma unroll
      for (int r6 = 0; r6 < 6; ++r6) { an[r6] = xng[2*py+r6] >> x0; az[r6] = xnz[2*py+r6] >> x0; }
      uint32_t hm = 0;
      for (int c = 0; c < 18; ++c) {
        const uint32_t wt = sW1[c] & 0x1FFFFFFu;
        const float B = __uint_as_float(wsu[CFP + c]);
        const float S = __uint_as_float(wsu[CFP + 18 + c]);
        const float T = __uint_as_float(wsu[CFP + 36 + c]);
        int best = -1000;
        #pragma unroll
        for (int dy = 0; dy < 2; ++dy)
          #pragma unroll
          for (int dx = 0; dx < 2; ++dx) {
            int cnt = 0, ng = 0;
            #pragma unroll
            for (int k = 0; k < 5; ++k) {
              const uint32_t nzr = (az[dy+k] >> dx) & 31u;
              const uint32_t sgr = (an[dy+k] >> dx) & 31u;
              const uint32_t wr  = (wt >> (5*k)) & 31u;
              cnt += __popc(nzr);
              ng  += __popc((sgr ^ wr) & nzr);
            }
            const int conv = cnt - 2*ng;
            best = best > conv ? best : conv;
          }
        if (negv(best, B, S, T)) hm |= 1u << c;
      }
      h1w[p] = hm;
    }
  }
  __threadfence_block();

  // ---- dense 96-bit im2col row segments ----
  for (int rr = 0; rr < 3; ++rr) {
    const int i = lane + 64*rr;
    if (i < 140) {
      const int row = i / 10, xx = i - row*10;
      const uint32_t* hp = &h1w[row*14 + xx];
      const uint32_t m0 = hp[0], m1 = hp[1], m2 = hp[2], m3 = hp[3], m4 = hp[4];
      uint4 sg4;
      sg4.x = m0 | (m1 << 18);
      sg4.y = (m1 >> 14) | (m2 << 4) | (m3 << 22);
      sg4.z = (m3 >> 10) | (m4 << 8);
      sg4.w = 0;
      seg[i] = sg4;
    }
  }
  __threadfence_block();

  // ---- stage 2: conv2 + pool + int thresholds (lane = (pos, ch-half)) ----
  if (lane < 50) {
    const int p = lane >> 1, half = lane & 1;
    const int py = p / 5, px = p - py*5;
    const int sb = py*20 + px*2;
    const uint4 s00=seg[sb],    s01=seg[sb+1],  s10=seg[sb+10], s11=seg[sb+11],
                s20=seg[sb+20], s21=seg[sb+21], s30=seg[sb+30], s31=seg[sb+31],
                s40=seg[sb+40], s41=seg[sb+41], s50=seg[sb+50], s51=seg[sb+51];
    uint32_t bits = 0;
    const int obase = half * 24;
    #pragma unroll 4
    for (int c = 0; c < 24; ++c) {
      const int o = obase + c;
      const uint4 W0 = sW2[o*4+0], W1 = sW2[o*4+1], W2q = sW2[o*4+2], W3q = sW2[o*4+3];
      int m00 = ROWM(s00,W0.x,W0.y,W0.z) + ROWM(s10,W0.w,W1.x,W1.y) + ROWM(s20,W1.z,W1.w,W2q.x)
              + ROWM(s30,W2q.y,W2q.z,W2q.w) + ROWM(s40,W3q.x,W3q.y,W3q.z);
      int m01 = ROWM(s01,W0.x,W0.y,W0.z) + ROWM(s11,W0.w,W1.x,W1.y) + ROWM(s21,W1.z,W1.w,W2q.x)
              + ROWM(s31,W2q.y,W2q.z,W2q.w) + ROWM(s41,W3q.x,W3q.y,W3q.z);
      int m10 = ROWM(s10,W0.x,W0.y,W0.z) + ROWM(s20,W0.w,W1.x,W1.y) + ROWM(s30,W1.z,W1.w,W2q.x)
              + ROWM(s40,W2q.y,W2q.z,W2q.w) + ROWM(s50,W3q.x,W3q.y,W3q.z);
      int m11 = ROWM(s11,W0.x,W0.y,W0.z) + ROWM(s21,W0.w,W1.x,W1.y) + ROWM(s31,W1.z,W1.w,W2q.x)
              + ROWM(s41,W2q.y,W2q.z,W2q.w) + ROWM(s51,W3q.x,W3q.y,W3q.z);
      const int mn = min(min(m00, m01), min(m10, m11));
      const uint32_t mw = W3q.w;
      const uint32_t bit = ((mn >= (int)(mw & 511u)) ? 1u : 0u) ^ ((mw >> 9) & 1u);
      bits |= bit << c;
    }
    h2w[p*2 + half] = bits;
  }
  __threadfence_block();

  // ---- stage 3: conv3 (48->120) via ballot -> wave-uniform 120-bit vector ----
  unsigned long long h3_01, h3_23;
  #pragma unroll
  for (int r = 0; r < 2; ++r) {
    const int o = lane + 64*r;
    bool pred = false;
    if (o < 120) {
      int mm0 = 0, mm1 = 0;
      #pragma unroll
      for (int w = 0; w < 50; w += 2) {
        mm0 += __popc(h2w[w]   ^ wsu[W3P + w*120 + o]);
        mm1 += __popc(h2w[w+1] ^ wsu[W3P + (w+1)*120 + o]);
      }
      const uint32_t mw = wsu[M3P + o];
      pred = ((((mm0 + mm1) >= (int)(mw & 2047u)) ? 1u : 0u) ^ (mw >> 11)) != 0u;
    }
    unsigned long long bb = __ballot(pred);
    if (r == 0) h3_01 = bb; else h3_23 = bb;
  }

  // ---- stage 4: fc1 (120->252) via ballot -> 252-bit vector in regs ----
  const uint32_t h3w0 = (uint32_t)h3_01, h3w1 = (uint32_t)(h3_01 >> 32),
                 h3w2 = (uint32_t)h3_23, h3w3 = (uint32_t)(h3_23 >> 32);
  uint32_t h4w[8];
  #pragma unroll
  for (int r = 0; r < 4; ++r) {
    const int o = lane + 64*r;
    bool pred = false;
    if (o < 252) {
      const int mm = __popc(h3w0 ^ wsu[FW1P + o])       + __popc(h3w1 ^ wsu[FW1P + 252 + o])
                   + __popc(h3w2 ^ wsu[FW1P + 504 + o]) + __popc(h3w3 ^ wsu[FW1P + 756 + o]);
      const uint32_t mw = wsu[M4P + o];
      pred = (((mm >= (int)(mw & 127u)) ? 1u : 0u) ^ (mw >> 7)) != 0u;
    }
    unsigned long long bb = __ballot(pred);
    h4w[2*r]   = (uint32_t)bb;
    h4w[2*r+1] = (uint32_t)(bb >> 32);
  }

  // ---- stage 5: fc2 + bn + log_softmax (shuffle reduce over 16-lane group) ----
  float vv = -1e30f;
  if (lane < 10) {
    int mm = 0;
    #pragma unroll
    for (int wi = 0; wi < 8; ++wi)
      mm += __popc(h4w[wi] ^ wsu[FW2P + wi*10 + lane]);
    const int dot = 252 - 2*mm;
    const float B = __uint_as_float(wsu[CFP + 54 + lane]);
    const float S = __uint_as_float(wsu[CFP + 64 + lane]);
    const float T = __uint_as_float(wsu[CFP + 74 + lane]);
    float v = __fadd_rn((float)dot, B);
    v = __fmul_rn(v, S);
    vv = __fadd_rn(v, T);
  }
  float mx = vv;
  #pragma unroll
  for (int d = 1; d < 16; d <<= 1)
    mx = fmaxf(mx, __shfl_xor(mx, d, 16));
  const float sh = __fsub_rn(vv, mx);
  float s = expf(sh);
  #pragma unroll
  for (int d = 1; d < 16; d <<= 1)
    s = __fadd_rn(s, __shfl_xor(s, d, 16));
  if (lane < 10)
    out[(size_t)img*10 + lane] = __fsub_rn(sh, logf(s));
}

extern "C" void kernel_launch(void* const* d_in, const int* in_sizes, int n_in,
                              void* d_out, int out_size, void* d_ws, size_t ws_size,
                              hipStream_t stream)
{
  const float* x   = (const float*)d_in[0];
  const float* w1  = (const float*)d_in[1];
  const float* cb1 = (const float*)d_in[2];
  const float* g1  = (const float*)d_in[3];
  const float* be1 = (const float*)d_in[4];
  const float* m1  = (const float*)d_in[5];
  const float* v1  = (const float*)d_in[6];
  const float* w2  = (const float*)d_in[7];
  const float* cb2 = (const float*)d_in[8];
  const float* g2  = (const float*)d_in[9];
  const float* be2 = (const float*)d_in[10];
  const float* m2  = (const float*)d_in[11];
  const float* v2  = (const float*)d_in[12];
  const float* w3  = (const float*)d_in[13];
  const float* cb3 = (const float*)d_in[14];
  const float* g3  = (const float*)d_in[15];
  const float* be3 = (const float*)d_in[16];
  const float* m3  = (const float*)d_in[17];
  const float* v3  = (const float*)d_in[18];
  const float* fw1 = (const float*)d_in[19];
  const float* fb1 = (const float*)d_in[20];
  const float* g4  = (const float*)d_in[21];
  const float* be4 = (const float*)d_in[22];
  const float* m4  = (const float*)d_in[23];
  const float* v4  = (const float*)d_in[24];
  const float* fw2 = (const float*)d_in[25];
  const float* fb2 = (const float*)d_in[26];
  const float* g5  = (const float*)d_in[27];
  const float* be5 = (const float*)d_in[28];
  const float* m5  = (const float*)d_in[29];
  const float* v5  = (const float*)d_in[30];

  uint32_t* wsu = (uint32_t*)d_ws;
  float* out = (float*)d_out;

  hipLaunchKernelGGL(pack_kernel, dim3(30), dim3(256), 0, stream,
                     w1, w2, w3, fw1, fw2,
                     cb1, g1, be1, m1, v1,
                     cb2, g2, be2, m2, v2,
                     cb3, g3, be3, m3, v3,
                     fb1, g4, be4, m4, v4,
                     fb2, g5, be5, m5, v5,
                     wsu);

  hipLaunchKernelGGL(lenet_main, dim3(1024), dim3(256), 0, stream,
                     x, wsu, out);
}

// Round 4
// 63.674 us; speedup vs baseline: 1.3439x; 1.0971x over previous
//
#include <hip/hip_runtime.h>
#include <stdint.h>

// ---------------- ws layout (u32 indices) ----------------
#define W1P   0      // 18   per channel: wt25 (bits 0..24) | M<<25
#define INV1  18     // 1    bit c = inv_c for stage1
#define W2P   32     // 768  48 o x 16 words: dense 480-bit weights + [15]=M|inv<<9
#define W3P   800    // 6000 [w*120 + o], w = pos*2 + h, bit j = ch c = h*24+j (j<24)
#define M3P   6800   // 120  M | inv<<11
#define FW1P  6920   // 1008 [wi*252 + o], bits j: col = wi*32+j (<120)
#define M4P   7928   // 252  M | inv<<7
#define FW2P  8180   // 80   [wi*10 + o], bits j: col = wi*32+j (<252)
#define CFP   8260   // 84 floats: B1[18] S1[18] T1[18] B5[10] S5[10] T5[10]

__device__ inline bool negv(int dot, float B, float S, float T) {
  float v = __fadd_rn((float)dot, B);
  v = __fmul_rn(v, S);
  v = __fadd_rn(v, T);
  return v < 0.0f;
}

// neg-set over m (mismatch count, dot = tot-2m) is a prefix or suffix
// (affine-monotone in m). neg(m) == ((m >= M) ^ inv). Binary search.
__device__ inline void scanMT(float B, float S, float T, int tot, int& M, int& inv) {
  bool b0 = negv(tot, B, S, T);     // m = 0
  bool be = negv(-tot, B, S, T);    // m = tot
  if (b0 == be) { M = 0; inv = b0 ? 0 : 1; return; }
  int lo = 0, hi = tot;
  while (hi - lo > 1) {
    int mid = (lo + hi) >> 1;
    if (negv(tot - 2*mid, B, S, T) == b0) lo = mid; else hi = mid;
  }
  M = hi; inv = b0 ? 1 : 0;
}

__device__ inline float bnS(float g, float v) {
  return __fdiv_rn(g, __fsqrt_rn(__fadd_rn(v, 1e-5f)));
}
__device__ inline float bnT(float be, float m, float s) {
  return __fsub_rn(be, __fmul_rn(m, s));
}

__global__ __launch_bounds__(256) void pack_kernel(
    const float* __restrict__ w1, const float* __restrict__ w2, const float* __restrict__ w3,
    const float* __restrict__ fw1, const float* __restrict__ fw2,
    const float* __restrict__ cb1, const float* __restrict__ g1, const float* __restrict__ be1,
    const float* __restrict__ m1, const float* __restrict__ v1,
    const float* __restrict__ cb2, const float* __restrict__ g2, const float* __restrict__ be2,
    const float* __restrict__ m2, const float* __restrict__ v2,
    const float* __restrict__ cb3, const float* __restrict__ g3, const float* __restrict__ be3,
    const float* __restrict__ m3, const float* __restrict__ v3,
    const float* __restrict__ fb1, const float* __restrict__ g4, const float* __restrict__ be4,
    const float* __restrict__ m4, const float* __restrict__ v4,
    const float* __restrict__ fb2, const float* __restrict__ g5, const float* __restrict__ be5,
    const float* __restrict__ m5, const float* __restrict__ v5,
    uint32_t* __restrict__ wsu)
{
  const int tid = blockIdx.x * 256 + threadIdx.x;

  if (tid < 18) {                         // w1 packed 25-bit + M
    int c = tid;
    uint32_t wt = 0;
    for (int ky = 0; ky < 5; ++ky)
      for (int kx = 0; kx < 5; ++kx)
        if (w1[c*25 + ky*5 + kx] < 0.0f) wt |= 1u << (ky*5 + kx);
    float S = bnS(g1[c], v1[c]);
    float B = cb1[c];
    float T = bnT(be1[c], m1[c], S);
    int M, iv; scanMT(B, S, T, 25, M, iv);
    wsu[W1P + c] = wt | ((uint32_t)M << 25);
  } else if (tid == 18) {                 // inv mask for stage1
    uint32_t mask = 0;
    for (int c = 0; c < 18; ++c) {
      float S = bnS(g1[c], v1[c]);
      float B = cb1[c];
      float T = bnT(be1[c], m1[c], S);
      int M, iv; scanMT(B, S, T, 25, M, iv);
      if (iv) mask |= 1u << c;
    }
    wsu[INV1] = mask;
  } else if (tid >= 32 && tid < 80) {     // w2 dense pack + M2
    int o = tid - 32;
    uint32_t W[16];
    for (int ky = 0; ky < 5; ++ky) {
      uint32_t mw[5];
      for (int kx = 0; kx < 5; ++kx) {
        uint32_t b = 0;
        for (int c = 0; c < 18; ++c)
          if (w2[(o*18 + c)*25 + ky*5 + kx] < 0.0f) b |= 1u << c;
        mw[kx] = b;
      }
      W[3*ky+0] = mw[0] | (mw[1] << 18);
      W[3*ky+1] = (mw[1] >> 14) | (mw[2] << 4) | (mw[3] << 22);
      W[3*ky+2] = (mw[3] >> 10) | (mw[4] << 8);
    }
    float S = bnS(g2[o], v2[o]);
    float B = cb2[o];
    float T = bnT(be2[o], m2[o], S);
    int M, iv; scanMT(B, S, T, 450, M, iv);
    W[15] = (uint32_t)M | ((uint32_t)iv << 9);
    for (int q = 0; q < 16; ++q) wsu[W2P + o*16 + q] = W[q];
  } else if (tid >= 96 && tid < 6096) {   // w3 bits, transposed [w][o], 24ch/word
    int i = tid - 96;
    int w = i / 120, o = i % 120;
    int pos = w >> 1, h = w & 1;
    uint32_t b = 0;
    for (int j = 0; j < 24; ++j) {
      int c = h*24 + j;
      if (w3[(o*48 + c)*25 + pos] < 0.0f) b |= 1u << j;
    }
    wsu[W3P + i] = b;
  } else if (tid >= 6096 && tid < 6216) { // M3
    int o = tid - 6096;
    float S = bnS(g3[o], v3[o]);
    float B = cb3[o];
    float T = bnT(be3[o], m3[o], S);
    int M, iv; scanMT(B, S, T, 1200, M, iv);
    wsu[M3P + o] = (uint32_t)M | ((uint32_t)iv << 11);
  } else if (tid >= 6216 && tid < 7224) { // fw1 bits, transposed
    int i = tid - 6216;
    int wi = i / 252, o = i % 252;
    uint32_t b = 0;
    for (int j = 0; j < 32; ++j) {
      int col = wi*32 + j;
      if (col < 120 && fw1[o*120 + col] < 0.0f) b |= 1u << j;
    }
    wsu[FW1P + i] = b;
  } else if (tid >= 7224 && tid < 7476) { // M4
    int o = tid - 7224;
    float S = bnS(g4[o], v4[o]);
    float B = fb1[o];
    float T = bnT(be4[o], m4[o], S);
    int M, iv; scanMT(B, S, T, 120, M, iv);
    wsu[M4P + o] = (uint32_t)M | ((uint32_t)iv << 7);
  } else if (tid >= 7476 && tid < 7556) { // fw2 bits, transposed
    int i = tid - 7476;
    int wi = i / 10, o = i % 10;
    uint32_t b = 0;
    for (int j = 0; j < 32; ++j) {
      int col = wi*32 + j;
      if (col < 252 && fw2[o*252 + col] < 0.0f) b |= 1u << j;
    }
    wsu[FW2P + i] = b;
  } else if (tid >= 7556 && tid < 7640) { // CF floats
    int j = tid - 7556;
    float outv;
    if (j < 18) outv = cb1[j];
    else if (j < 36) { int c = j - 18; outv = bnS(g1[c], v1[c]); }
    else if (j < 54) { int c = j - 36; float s = bnS(g1[c], v1[c]); outv = bnT(be1[c], m1[c], s); }
    else if (j < 64) { int c = j - 54; outv = fb2[c]; }
    else if (j < 74) { int c = j - 64; outv = bnS(g5[c], v5[c]); }
    else             { int c = j - 74; float s = bnS(g5[c], v5[c]); outv = bnT(be5[c], m5[c], s); }
    wsu[CFP + j] = __float_as_uint(outv);
  }
}

#define RM(r,cx,k) (__popc(sw[r][cx][0]^wk[(k)*3+0]) + __popc(sw[r][cx][1]^wk[(k)*3+1]) + __popc(sw[r][cx][2]^wk[(k)*3+2]))

__global__ __launch_bounds__(256) void lenet_main(
    const float* __restrict__ x, const uint32_t* __restrict__ wsu,
    float* __restrict__ out)
{
  __shared__ uint4    sW2[192];      // 48 o x 4 uint4
  __shared__ uint32_t xng[32], xnz[32];
  __shared__ uint32_t h1w[196];
  __shared__ uint32_t segw[420];     // 140 segments x 3 words (stride 3)
  __shared__ uint32_t h2w[50];
  __shared__ uint32_t h3[4];
  __shared__ uint32_t h4[8];
  __shared__ int      zflag;

  const int t = threadIdx.x;
  const int lane = t & 63, wid = t >> 6;
  const int img = blockIdx.x;

  if (t < 192) sW2[t] = ((const uint4*)(wsu + W2P))[t];
  if (t == 192) zflag = 0;
  __syncthreads();

  // ---- input pack: thread -> (row = t>>3, quad k = t&7), 4 px each ----
  {
    const float* xim = x + (size_t)img * 1024;
    const int row = t >> 3, k = t & 7;
    const float4 f = ((const float4*)(xim + row*32))[k];
    const uint32_t u0 = __float_as_uint(f.x), u1 = __float_as_uint(f.y),
                   u2 = __float_as_uint(f.z), u3 = __float_as_uint(f.w);
    uint32_t ng = (u0>>31) | ((u1>>31)<<1) | ((u2>>31)<<2) | ((u3>>31)<<3);
    uint32_t nz = (uint32_t)((u0<<1)!=0u) | ((uint32_t)((u1<<1)!=0u)<<1)
                | ((uint32_t)((u2<<1)!=0u)<<2) | ((uint32_t)((u3<<1)!=0u)<<3);
    ng <<= 4*k; nz <<= 4*k;
    ng |= __shfl_xor(ng, 1);  nz |= __shfl_xor(nz, 1);
    ng |= __shfl_xor(ng, 2);  nz |= __shfl_xor(nz, 2);
    ng |= __shfl_xor(ng, 4);  nz |= __shfl_xor(nz, 4);
    if (k == 0) {
      xng[row] = ng;
      xnz[row] = nz;
      if (nz != 0xFFFFFFFFu) atomicOr(&zflag, 1);
    }
  }
  __syncthreads();

  // ---- stage 1: conv1 + pool + int-threshold sign (196 threads) ----
  const bool zer = (zflag != 0);
  if (t < 196) {
    const int py = t / 14, px = t - py*14;
    const int x0 = 2*px, y0 = 2*py;
    uint32_t hm = 0;
    if (!zer) {
      const uint32_t a0 = xng[y0+0] >> x0, a1 = xng[y0+1] >> x0,
                     a2 = xng[y0+2] >> x0, a3 = xng[y0+3] >> x0,
                     a4 = xng[y0+4] >> x0, a5 = xng[y0+5] >> x0;
      const uint32_t w00 = (a0&31u) | ((a1&31u)<<5) | ((a2&31u)<<10) | ((a3&31u)<<15) | ((a4&31u)<<20);
      const uint32_t w01 = ((a0>>1)&31u) | (((a1>>1)&31u)<<5) | (((a2>>1)&31u)<<10) | (((a3>>1)&31u)<<15) | (((a4>>1)&31u)<<20);
      const uint32_t w10 = (a1&31u) | ((a2&31u)<<5) | ((a3&31u)<<10) | ((a4&31u)<<15) | ((a5&31u)<<20);
      const uint32_t w11 = ((a1>>1)&31u) | (((a2>>1)&31u)<<5) | (((a3>>1)&31u)<<10) | (((a4>>1)&31u)<<15) | (((a5>>1)&31u)<<20);
      const uint32_t iv1 = wsu[INV1];                 // scalar (uniform)
      #pragma unroll
      for (int c = 0; c < 18; ++c) {
        const uint32_t wd = wsu[W1P + c];             // scalar (uniform)
        const uint32_t wt = wd & 0x1FFFFFFu;
        const int M = (int)(wd >> 25);
        const int mn = min(min(__popc(w00^wt), __popc(w01^wt)),
                           min(__popc(w10^wt), __popc(w11^wt)));
        hm |= (mn >= M) ? (1u << c) : 0u;
      }
      hm ^= iv1;
    } else {                                  // exact-zero-aware float path (rare)
      uint32_t an[6], az[6];
      #pragma unroll
      for (int r6 = 0; r6 < 6; ++r6) { an[r6] = xng[y0+r6] >> x0; az[r6] = xnz[y0+r6] >> x0; }
      for (int c = 0; c < 18; ++c) {
        const uint32_t wt = wsu[W1P + c] & 0x1FFFFFFu;
        const float B = __uint_as_float(wsu[CFP + c]);
        const float S = __uint_as_float(wsu[CFP + 18 + c]);
        const float T = __uint_as_float(wsu[CFP + 36 + c]);
        int best = -1000;
        #pragma unroll
        for (int dy = 0; dy < 2; ++dy)
          #pragma unroll
          for (int dx = 0; dx < 2; ++dx) {
            int cnt = 0, ng = 0;
            #pragma unroll
            for (int k = 0; k < 5; ++k) {
              const uint32_t nzr = (az[dy+k] >> dx) & 31u;
              const uint32_t sgr = (an[dy+k] >> dx) & 31u;
              const uint32_t wr  = (wt >> (5*k)) & 31u;
              cnt += __popc(nzr);
              ng  += __popc((sgr ^ wr) & nzr);
            }
            const int conv = cnt - 2*ng;
            best = best > conv ? best : conv;
          }
        if (negv(best, B, S, T)) hm |= 1u << c;
      }
    }
    h1w[t] = hm;
  }
  __syncthreads();

  // ---- dense 90-bit im2col row segments, stride-3 words ----
  if (t < 140) {
    const int row = t / 10, xx = t - row*10;
    const uint32_t* hp = &h1w[row*14 + xx];
    const uint32_t m0 = hp[0], m1 = hp[1], m2 = hp[2], m3 = hp[3], m4 = hp[4];
    segw[t*3+0] = m0 | (m1 << 18);
    segw[t*3+1] = (m1 >> 14) | (m2 << 4) | (m3 << 22);
    segw[t*3+2] = (m3 >> 10) | (m4 << 8);
  }
  __syncthreads();

  // ---- stage 2: conv2 + pool + int thresholds (200 threads: 25 pos x 8 grp) ----
  if (t < 200) {
    const int p = t >> 3, g = t & 7;
    const int py = p / 5, px = p - py*5;
    const int sb3 = py*60 + px*6;           // (2py*10 + 2px)*3
    uint32_t sw[6][2][3];
    #pragma unroll
    for (int r = 0; r < 6; ++r)
      #pragma unroll
      for (int cx = 0; cx < 2; ++cx)
        #pragma unroll
        for (int w = 0; w < 3; ++w)
          sw[r][cx][w] = segw[sb3 + (r*10 + cx)*3 + w];

    uint32_t bits = 0;
    #pragma unroll
    for (int j = 0; j < 6; ++j) {
      const int o = g*6 + j;
      const uint4 W0 = sW2[o*4+0], W1 = sW2[o*4+1], W2q = sW2[o*4+2], W3q = sW2[o*4+3];
      uint32_t wk[15];
      wk[0]=W0.x; wk[1]=W0.y; wk[2]=W0.z; wk[3]=W0.w; wk[4]=W1.x;
      wk[5]=W1.y; wk[6]=W1.z; wk[7]=W1.w; wk[8]=W2q.x; wk[9]=W2q.y;
      wk[10]=W2q.z; wk[11]=W2q.w; wk[12]=W3q.x; wk[13]=W3q.y; wk[14]=W3q.z;
      const int m00 = RM(0,0,0)+RM(1,0,1)+RM(2,0,2)+RM(3,0,3)+RM(4,0,4);
      const int m01 = RM(0,1,0)+RM(1,1,1)+RM(2,1,2)+RM(3,1,3)+RM(4,1,4);
      const int m10 = RM(1,0,0)+RM(2,0,1)+RM(3,0,2)+RM(4,0,3)+RM(5,0,4);
      const int m11 = RM(1,1,0)+RM(2,1,1)+RM(3,1,2)+RM(4,1,3)+RM(5,1,4);
      const int mn = min(min(m00, m01), min(m10, m11));
      const uint32_t mw = W3q.w;
      const uint32_t bit = ((mn >= (int)(mw & 511u)) ? 1u : 0u) ^ ((mw >> 9) & 1u);
      bits |= bit << j;
    }
    // assemble 48 bits per position via shfl-or within the 8-lane group
    uint32_t v = bits << ((g & 3) * 6);
    v |= __shfl_xor(v, 1);
    v |= __shfl_xor(v, 2);
    if ((g & 3) == 0) h2w[p*2 + (g >> 2)] = v;   // 24-bit words, ch = h*24+bit
  }
  __syncthreads();

  // ---- stage 3: conv3 (48->120), ballot -> h3 bits (120 threads) ----
  if (t < 120) {
    const int o = t;
    int mm0 = 0, mm1 = 0;
    #pragma unroll 10
    for (int w = 0; w < 50; w += 2) {
      mm0 += __popc(h2w[w]   ^ wsu[W3P + w*120 + o]);
      mm1 += __popc(h2w[w+1] ^ wsu[W3P + (w+1)*120 + o]);
    }
    const uint32_t mw = wsu[M3P + o];
    const bool pred = ((((mm0 + mm1) >= (int)(mw & 2047u)) ? 1u : 0u) ^ (mw >> 11)) != 0u;
    unsigned long long bb = __ballot(pred);
    if (lane == 0) {
      h3[wid*2]   = (uint32_t)bb;
      h3[wid*2+1] = (uint32_t)(bb >> 32);
    }
  }
  __syncthreads();

  // ---- stage 4: fc1 (120->252), ballot -> h4 bits (252 threads) ----
  if (t < 252) {
    const int o = t;
    const int mm = __popc(h3[0] ^ wsu[FW1P + o])       + __popc(h3[1] ^ wsu[FW1P + 252 + o])
                 + __popc(h3[2] ^ wsu[FW1P + 504 + o]) + __popc(h3[3] ^ wsu[FW1P + 756 + o]);
    const uint32_t mw = wsu[M4P + o];
    const bool pred = (((mm >= (int)(mw & 127u)) ? 1u : 0u) ^ (mw >> 7)) != 0u;
    unsigned long long bb = __ballot(pred);
    if (lane == 0) {
      h4[wid*2]   = (uint32_t)bb;
      h4[wid*2+1] = (uint32_t)(bb >> 32);
    }
  }
  __syncthreads();

  // ---- stage 5: fc2 + bn + log_softmax (wave 0, 16 lanes) ----
  if (t < 16) {
    float vv = -1e30f;
    if (t < 10) {
      int mm = 0;
      #pragma unroll
      for (int wi = 0; wi < 8; ++wi)
        mm += __popc(h4[wi] ^ wsu[FW2P + wi*10 + t]);
      const int dot = 252 - 2*mm;
      const float B = __uint_as_float(wsu[CFP + 54 + t]);
      const float S = __uint_as_float(wsu[CFP + 64 + t]);
      const float T = __uint_as_float(wsu[CFP + 74 + t]);
      float v = __fadd_rn((float)dot, B);
      v = __fmul_rn(v, S);
      vv = __fadd_rn(v, T);
    }
    float mx = vv;
    #pragma unroll
    for (int d = 1; d < 16; d <<= 1)
      mx = fmaxf(mx, __shfl_xor(mx, d, 16));
    const float sh = __fsub_rn(vv, mx);
    float s = expf(sh);
    #pragma unroll
    for (int d = 1; d < 16; d <<= 1)
      s = __fadd_rn(s, __shfl_xor(s, d, 16));
    if (t < 10)
      out[(size_t)img*10 + t] = __fsub_rn(sh, logf(s));
  }
}

extern "C" void kernel_launch(void* const* d_in, const int* in_sizes, int n_in,
                              void* d_out, int out_size, void* d_ws, size_t ws_size,
                              hipStream_t stream)
{
  const float* x   = (const float*)d_in[0];
  const float* w1  = (const float*)d_in[1];
  const float* cb1 = (const float*)d_in[2];
  const float* g1  = (const float*)d_in[3];
  const float* be1 = (const float*)d_in[4];
  const float* m1  = (const float*)d_in[5];
  const float* v1  = (const float*)d_in[6];
  const float* w2  = (const float*)d_in[7];
  const float* cb2 = (const float*)d_in[8];
  const float* g2  = (const float*)d_in[9];
  const float* be2 = (const float*)d_in[10];
  const float* m2  = (const float*)d_in[11];
  const float* v2  = (const float*)d_in[12];
  const float* w3  = (const float*)d_in[13];
  const float* cb3 = (const float*)d_in[14];
  const float* g3  = (const float*)d_in[15];
  const float* be3 = (const float*)d_in[16];
  const float* m3  = (const float*)d_in[17];
  const float* v3  = (const float*)d_in[18];
  const float* fw1 = (const float*)d_in[19];
  const float* fb1 = (const float*)d_in[20];
  const float* g4  = (const float*)d_in[21];
  const float* be4 = (const float*)d_in[22];
  const float* m4  = (const float*)d_in[23];
  const float* v4  = (const float*)d_in[24];
  const float* fw2 = (const float*)d_in[25];
  const float* fb2 = (const float*)d_in[26];
  const float* g5  = (const float*)d_in[27];
  const float* be5 = (const float*)d_in[28];
  const float* m5  = (const float*)d_in[29];
  const float* v5  = (const float*)d_in[30];

  uint32_t* wsu = (uint32_t*)d_ws;
  float* out = (float*)d_out;

  hipLaunchKernelGGL(pack_kernel, dim3(30), dim3(256), 0, stream,
                     w1, w2, w3, fw1, fw2,
                     cb1, g1, be1, m1, v1,
                     cb2, g2, be2, m2, v2,
                     cb3, g3, be3, m3, v3,
                     fb1, g4, be4, m4, v4,
                     fb2, g5, be5, m5, v5,
                     wsu);

  hipLaunchKernelGGL(lenet_main, dim3(4096), dim3(256), 0, stream,
                     x, wsu, out);
}

// Round 5
// 57.698 us; speedup vs baseline: 1.4831x; 1.1036x over previous
//
#include <hip/hip_runtime.h>
#include <stdint.h>

// ---------------- ws layout (u32 indices) ----------------
#define W1P   0      // 18   per channel: wt25 (bits 0..24) | M<<25
#define INV1  18     // 1    bit c = inv_c for stage1
#define W2P   32     // 768  48 o x 16 words: dense 480-bit weights + [15]=M|inv<<9
#define W3P   800    // 120 o x 56 words: word s = w + (w>=25?3:0), w = pos*2 + hc (24ch bits)
#define M3P   7520   // 120  M | inv<<11
#define FW1P  7640   // 252 o x 4 words (cols wi*32+j < 120)
#define M4P   8648   // 252  M | inv<<7
#define FW2P  8900   // 80   [wi*10 + o], bits j: col = wi*32+j (<252)
#define CFP   8980   // 84 floats: B1[18] S1[18] T1[18] B5[10] S5[10] T5[10]

__device__ inline bool negv(int dot, float B, float S, float T) {
  float v = __fadd_rn((float)dot, B);
  v = __fmul_rn(v, S);
  v = __fadd_rn(v, T);
  return v < 0.0f;
}

// neg-set over m (mismatch count, dot = tot-2m) is a prefix or suffix
// (affine-monotone in m). neg(m) == ((m >= M) ^ inv). Binary search.
__device__ inline void scanMT(float B, float S, float T, int tot, int& M, int& inv) {
  bool b0 = negv(tot, B, S, T);     // m = 0
  bool be = negv(-tot, B, S, T);    // m = tot
  if (b0 == be) { M = 0; inv = b0 ? 0 : 1; return; }
  int lo = 0, hi = tot;
  while (hi - lo > 1) {
    int mid = (lo + hi) >> 1;
    if (negv(tot - 2*mid, B, S, T) == b0) lo = mid; else hi = mid;
  }
  M = hi; inv = b0 ? 1 : 0;
}

__device__ inline float bnS(float g, float v) {
  return __fdiv_rn(g, __fsqrt_rn(__fadd_rn(v, 1e-5f)));
}
__device__ inline float bnT(float be, float m, float s) {
  return __fsub_rn(be, __fmul_rn(m, s));
}

__global__ __launch_bounds__(256) void pack_kernel(
    const float* __restrict__ w1, const float* __restrict__ w2, const float* __restrict__ w3,
    const float* __restrict__ fw1, const float* __restrict__ fw2,
    const float* __restrict__ cb1, const float* __restrict__ g1, const float* __restrict__ be1,
    const float* __restrict__ m1, const float* __restrict__ v1,
    const float* __restrict__ cb2, const float* __restrict__ g2, const float* __restrict__ be2,
    const float* __restrict__ m2, const float* __restrict__ v2,
    const float* __restrict__ cb3, const float* __restrict__ g3, const float* __restrict__ be3,
    const float* __restrict__ m3, const float* __restrict__ v3,
    const float* __restrict__ fb1, const float* __restrict__ g4, const float* __restrict__ be4,
    const float* __restrict__ m4, const float* __restrict__ v4,
    const float* __restrict__ fb2, const float* __restrict__ g5, const float* __restrict__ be5,
    const float* __restrict__ m5, const float* __restrict__ v5,
    uint32_t* __restrict__ wsu)
{
  const int tid = blockIdx.x * 256 + threadIdx.x;

  if (tid < 18) {                         // w1 packed 25-bit + M
    int c = tid;
    uint32_t wt = 0;
    for (int ky = 0; ky < 5; ++ky)
      for (int kx = 0; kx < 5; ++kx)
        if (w1[c*25 + ky*5 + kx] < 0.0f) wt |= 1u << (ky*5 + kx);
    float S = bnS(g1[c], v1[c]);
    float B = cb1[c];
    float T = bnT(be1[c], m1[c], S);
    int M, iv; scanMT(B, S, T, 25, M, iv);
    wsu[W1P + c] = wt | ((uint32_t)M << 25);
  } else if (tid == 18) {                 // inv mask for stage1
    uint32_t mask = 0;
    for (int c = 0; c < 18; ++c) {
      float S = bnS(g1[c], v1[c]);
      float B = cb1[c];
      float T = bnT(be1[c], m1[c], S);
      int M, iv; scanMT(B, S, T, 25, M, iv);
      if (iv) mask |= 1u << c;
    }
    wsu[INV1] = mask;
  } else if (tid >= 32 && tid < 80) {     // w2 dense pack + M2
    int o = tid - 32;
    uint32_t W[16];
    for (int ky = 0; ky < 5; ++ky) {
      uint32_t mw[5];
      for (int kx = 0; kx < 5; ++kx) {
        uint32_t b = 0;
        for (int c = 0; c < 18; ++c)
          if (w2[(o*18 + c)*25 + ky*5 + kx] < 0.0f) b |= 1u << c;
        mw[kx] = b;
      }
      W[3*ky+0] = mw[0] | (mw[1] << 18);
      W[3*ky+1] = (mw[1] >> 14) | (mw[2] << 4) | (mw[3] << 22);
      W[3*ky+2] = (mw[3] >> 10) | (mw[4] << 8);
    }
    float S = bnS(g2[o], v2[o]);
    float B = cb2[o];
    float T = bnT(be2[o], m2[o], S);
    int M, iv; scanMT(B, S, T, 450, M, iv);
    W[15] = (uint32_t)M | ((uint32_t)iv << 9);
    for (int q = 0; q < 16; ++q) wsu[W2P + o*16 + q] = W[q];
  } else if (tid >= 96 && tid < 6096) {   // w3 bits, [o][56] layout, 24ch/word
    int i = tid - 96;
    int o = i / 50, w = i % 50;
    int pos = w >> 1, hc = w & 1;
    uint32_t b = 0;
    for (int j = 0; j < 24; ++j) {
      int c = hc*24 + j;
      if (w3[(o*48 + c)*25 + pos] < 0.0f) b |= 1u << j;
    }
    wsu[W3P + o*56 + w + (w >= 25 ? 3 : 0)] = b;
  } else if (tid >= 6096 && tid < 6216) { // M3
    int o = tid - 6096;
    float S = bnS(g3[o], v3[o]);
    float B = cb3[o];
    float T = bnT(be3[o], m3[o], S);
    int M, iv; scanMT(B, S, T, 1200, M, iv);
    wsu[M3P + o] = (uint32_t)M | ((uint32_t)iv << 11);
  } else if (tid >= 6216 && tid < 7224) { // fw1 bits, [o][4] layout
    int i = tid - 6216;
    int wi = i / 252, o = i % 252;
    uint32_t b = 0;
    for (int j = 0; j < 32; ++j) {
      int col = wi*32 + j;
      if (col < 120 && fw1[o*120 + col] < 0.0f) b |= 1u << j;
    }
    wsu[FW1P + o*4 + wi] = b;
  } else if (tid >= 7224 && tid < 7476) { // M4
    int o = tid - 7224;
    float S = bnS(g4[o], v4[o]);
    float B = fb1[o];
    float T = bnT(be4[o], m4[o], S);
    int M, iv; scanMT(B, S, T, 120, M, iv);
    wsu[M4P + o] = (uint32_t)M | ((uint32_t)iv << 7);
  } else if (tid >= 7476 && tid < 7556) { // fw2 bits, transposed
    int i = tid - 7476;
    int wi = i / 10, o = i % 10;
    uint32_t b = 0;
    for (int j = 0; j < 32; ++j) {
      int col = wi*32 + j;
      if (col < 252 && fw2[o*252 + col] < 0.0f) b |= 1u << j;
    }
    wsu[FW2P + i] = b;
  } else if (tid >= 7556 && tid < 7640) { // CF floats
    int j = tid - 7556;
    float outv;
    if (j < 18) outv = cb1[j];
    else if (j < 36) { int c = j - 18; outv = bnS(g1[c], v1[c]); }
    else if (j < 54) { int c = j - 36; float s = bnS(g1[c], v1[c]); outv = bnT(be1[c], m1[c], s); }
    else if (j < 64) { int c = j - 54; outv = fb2[c]; }
    else if (j < 74) { int c = j - 64; outv = bnS(g5[c], v5[c]); }
    else             { int c = j - 74; float s = bnS(g5[c], v5[c]); outv = bnT(be5[c], m5[c], s); }
    wsu[CFP + j] = __float_as_uint(outv);
  }
}

__device__ __forceinline__ int rowm(uint4 s, uint32_t a, uint32_t b, uint32_t c) {
  return __popc(s.x ^ a) + __popc(s.y ^ b) + __popc(s.z ^ c);
}

__global__ __launch_bounds__(256) void lenet_main(
    const float* __restrict__ x, const uint32_t* __restrict__ wsu,
    float* __restrict__ out)
{
  __shared__ uint4    sW2[240];      // 48 o x 5 uint4 (stride-5 pad: 2-way max conflict)
  __shared__ uint32_t xng[32], xnz[32];
  __shared__ uint32_t h1w[196];
  __shared__ __align__(16) uint4 seg[140];   // [row*10+x] dense 90-bit, 16B aligned
  __shared__ uint32_t h2w[50];
  __shared__ uint32_t h3[4];
  __shared__ uint32_t h4[8];
  __shared__ int      zflag;

  const int t = threadIdx.x;
  const int lane = t & 63, wid = t >> 6;
  const int img = blockIdx.x;

  if (t < 192) sW2[(t >> 2)*5 + (t & 3)] = ((const uint4*)(wsu + W2P))[t];
  if (t < 50)  h2w[t] = 0;
  if (t == 192) zflag = 0;
  __syncthreads();

  // ---- input pack: thread -> (row = t>>3, quad k = t&7), 4 px each ----
  {
    const float* xim = x + (size_t)img * 1024;
    const int row = t >> 3, k = t & 7;
    const float4 f = ((const float4*)(xim + row*32))[k];
    const uint32_t u0 = __float_as_uint(f.x), u1 = __float_as_uint(f.y),
                   u2 = __float_as_uint(f.z), u3 = __float_as_uint(f.w);
    uint32_t ng = (u0>>31) | ((u1>>31)<<1) | ((u2>>31)<<2) | ((u3>>31)<<3);
    uint32_t nz = (uint32_t)((u0<<1)!=0u) | ((uint32_t)((u1<<1)!=0u)<<1)
                | ((uint32_t)((u2<<1)!=0u)<<2) | ((uint32_t)((u3<<1)!=0u)<<3);
    ng <<= 4*k; nz <<= 4*k;
    ng |= __shfl_xor(ng, 1);  nz |= __shfl_xor(nz, 1);
    ng |= __shfl_xor(ng, 2);  nz |= __shfl_xor(nz, 2);
    ng |= __shfl_xor(ng, 4);  nz |= __shfl_xor(nz, 4);
    if (k == 0) {
      xng[row] = ng;
      xnz[row] = nz;
      if (nz != 0xFFFFFFFFu) atomicOr(&zflag, 1);
    }
  }
  __syncthreads();

  // ---- stage 1: conv1 + pool + int-threshold sign (196 threads) ----
  const bool zer = (zflag != 0);
  if (t < 196) {
    const int py = t / 14, px = t - py*14;
    const int x0 = 2*px, y0 = 2*py;
    uint32_t hm = 0;
    if (!zer) {
      const uint32_t a0 = xng[y0+0] >> x0, a1 = xng[y0+1] >> x0,
                     a2 = xng[y0+2] >> x0, a3 = xng[y0+3] >> x0,
                     a4 = xng[y0+4] >> x0, a5 = xng[y0+5] >> x0;
      const uint32_t w00 = (a0&31u) | ((a1&31u)<<5) | ((a2&31u)<<10) | ((a3&31u)<<15) | ((a4&31u)<<20);
      const uint32_t w01 = ((a0>>1)&31u) | (((a1>>1)&31u)<<5) | (((a2>>1)&31u)<<10) | (((a3>>1)&31u)<<15) | (((a4>>1)&31u)<<20);
      const uint32_t w10 = (a1&31u) | ((a2&31u)<<5) | ((a3&31u)<<10) | ((a4&31u)<<15) | ((a5&31u)<<20);
      const uint32_t w11 = ((a1>>1)&31u) | (((a2>>1)&31u)<<5) | (((a3>>1)&31u)<<10) | (((a4>>1)&31u)<<15) | (((a5>>1)&31u)<<20);
      const uint32_t iv1 = wsu[INV1];                 // scalar (uniform)
      #pragma unroll
      for (int c = 0; c < 18; ++c) {
        const uint32_t wd = wsu[W1P + c];             // scalar (uniform)
        const uint32_t wt = wd & 0x1FFFFFFu;
        const int M = (int)(wd >> 25);
        const int mn = min(min(__popc(w00^wt), __popc(w01^wt)),
                           min(__popc(w10^wt), __popc(w11^wt)));
        hm |= (mn >= M) ? (1u << c) : 0u;
      }
      hm ^= iv1;
    } else {                                  // exact-zero-aware float path (rare)
      uint32_t an[6], az[6];
      #pragma unroll
      for (int r6 = 0; r6 < 6; ++r6) { an[r6] = xng[y0+r6] >> x0; az[r6] = xnz[y0+r6] >> x0; }
      for (int c = 0; c < 18; ++c) {
        const uint32_t wt = wsu[W1P + c] & 0x1FFFFFFu;
        const float B = __uint_as_float(wsu[CFP + c]);
        const float S = __uint_as_float(wsu[CFP + 18 + c]);
        const float T = __uint_as_float(wsu[CFP + 36 + c]);
        int best = -1000;
        #pragma unroll
        for (int dy = 0; dy < 2; ++dy)
          #pragma unroll
          for (int dx = 0; dx < 2; ++dx) {
            int cnt = 0, ng = 0;
            #pragma unroll
            for (int k = 0; k < 5; ++k) {
              const uint32_t nzr = (az[dy+k] >> dx) & 31u;
              const uint32_t sgr = (an[dy+k] >> dx) & 31u;
              const uint32_t wr  = (wt >> (5*k)) & 31u;
              cnt += __popc(nzr);
              ng  += __popc((sgr ^ wr) & nzr);
            }
            const int conv = cnt - 2*ng;
            best = best > conv ? best : conv;
          }
        if (negv(best, B, S, T)) hm |= 1u << c;
      }
    }
    h1w[t] = hm;
  }
  __syncthreads();

  // ---- dense 90-bit im2col row segments (uint4, 16B aligned) ----
  if (t < 140) {
    const int row = t / 10, xx = t - row*10;
    const uint32_t* hp = &h1w[row*14 + xx];
    const uint32_t m0 = hp[0], m1 = hp[1], m2 = hp[2], m3 = hp[3], m4 = hp[4];
    uint4 sg4;
    sg4.x = m0 | (m1 << 18);
    sg4.y = (m1 >> 14) | (m2 << 4) | (m3 << 22);
    sg4.z = (m3 >> 10) | (m4 << 8);
    sg4.w = 0;
    seg[t] = sg4;
  }
  __syncthreads();

  // ---- stage 2: conv2 + pool + int thresholds (250 thr: 25 pos x 10 grp) ----
  if (t < 250) {
    const int p = t / 10, g = t - (t / 10)*10;
    const int py = p / 5, px = p - py*5;
    const int sb = py*20 + px*2;
    uint4 sw[6][2];
    #pragma unroll
    for (int r = 0; r < 6; ++r) {
      sw[r][0] = seg[sb + r*10];
      sw[r][1] = seg[sb + r*10 + 1];
    }
    const int base = (g < 8) ? 5*g : (8 + 4*g);     // g=8 -> 40, g=9 -> 44
    uint32_t lo24 = 0, hi24 = 0;

    #pragma unroll
    for (int j = 0; j < 5; ++j) {
      if (j == 4 && g >= 8) break;
      const int o = base + j;
      const uint4 W0 = sW2[o*5+0], W1 = sW2[o*5+1], W2q = sW2[o*5+2], W3q = sW2[o*5+3];
      const int m00 = rowm(sw[0][0],W0.x,W0.y,W0.z) + rowm(sw[1][0],W0.w,W1.x,W1.y)
                    + rowm(sw[2][0],W1.z,W1.w,W2q.x) + rowm(sw[3][0],W2q.y,W2q.z,W2q.w)
                    + rowm(sw[4][0],W3q.x,W3q.y,W3q.z);
      const int m01 = rowm(sw[0][1],W0.x,W0.y,W0.z) + rowm(sw[1][1],W0.w,W1.x,W1.y)
                    + rowm(sw[2][1],W1.z,W1.w,W2q.x) + rowm(sw[3][1],W2q.y,W2q.z,W2q.w)
                    + rowm(sw[4][1],W3q.x,W3q.y,W3q.z);
      const int m10 = rowm(sw[1][0],W0.x,W0.y,W0.z) + rowm(sw[2][0],W0.w,W1.x,W1.y)
                    + rowm(sw[3][0],W1.z,W1.w,W2q.x) + rowm(sw[4][0],W2q.y,W2q.z,W2q.w)
                    + rowm(sw[5][0],W3q.x,W3q.y,W3q.z);
      const int m11 = rowm(sw[1][1],W0.x,W0.y,W0.z) + rowm(sw[2][1],W0.w,W1.x,W1.y)
                    + rowm(sw[3][1],W1.z,W1.w,W2q.x) + rowm(sw[4][1],W2q.y,W2q.z,W2q.w)
                    + rowm(sw[5][1],W3q.x,W3q.y,W3q.z);
      const int mn = min(min(m00, m01), min(m10, m11));
      const uint32_t mw = W3q.w;
      const uint32_t bit = ((mn >= (int)(mw & 511u)) ? 1u : 0u) ^ ((mw >> 9) & 1u);
      if (o < 24) lo24 |= bit << o; else hi24 |= bit << (o - 24);
    }
    if (lo24) atomicOr(&h2w[p*2],     lo24);
    if (hi24) atomicOr(&h2w[p*2 + 1], hi24);
  }
  __syncthreads();

  // ---- stage 3: conv3 (48->120), 240 thr = (o, K-half), shfl combine ----
  {
    bool pred = false;
    if (t < 240) {
      const int o = t >> 1, h = t & 1;
      const uint4* wp = (const uint4*)(wsu + W3P + o*56 + 28*h);
      const uint32_t* hv = &h2w[25*h];
      int mm0 = 0, mm1 = 0;
      #pragma unroll
      for (int q = 0; q < 6; ++q) {
        const uint4 ww = wp[q];
        mm0 += __popc(hv[q*4+0] ^ ww.x) + __popc(hv[q*4+2] ^ ww.z);
        mm1 += __popc(hv[q*4+1] ^ ww.y) + __popc(hv[q*4+3] ^ ww.w);
      }
      mm0 += __popc(hv[24] ^ ((const uint32_t*)wp)[24]);
      int mm = mm0 + mm1;
      mm += __shfl_xor(mm, 1);
      const uint32_t mw = wsu[M3P + o];
      pred = ((((mm) >= (int)(mw & 2047u)) ? 1u : 0u) ^ (mw >> 11)) != 0u;
    }
    unsigned long long bb = __ballot(pred && ((t & 1) == 0));
    // compress even bits -> 32-bit word for this wave's 32 o's
    unsigned long long xq = bb & 0x5555555555555555ull;
    xq = (xq | (xq >> 1))  & 0x3333333333333333ull;
    xq = (xq | (xq >> 2))  & 0x0F0F0F0F0F0F0F0Full;
    xq = (xq | (xq >> 4))  & 0x00FF00FF00FF00FFull;
    xq = (xq | (xq >> 8))  & 0x0000FFFF0000FFFFull;
    xq = (xq | (xq >> 16)) & 0x00000000FFFFFFFFull;
    if (lane == 0) h3[wid] = (uint32_t)xq;
  }
  __syncthreads();

  // ---- stage 4: fc1 (120->252), ballot -> h4 bits (252 threads) ----
  {
    bool pred = false;
    if (t < 252) {
      const uint4 fr = ((const uint4*)(wsu + FW1P))[t];
      const int mm = __popc(h3[0] ^ fr.x) + __popc(h3[1] ^ fr.y)
                   + __popc(h3[2] ^ fr.z) + __popc(h3[3] ^ fr.w);
      const uint32_t mw = wsu[M4P + t];
      pred = (((mm >= (int)(mw & 127u)) ? 1u : 0u) ^ (mw >> 7)) != 0u;
    }
    unsigned long long bb = __ballot(pred);
    if (lane == 0) {
      h4[wid*2]   = (uint32_t)bb;
      h4[wid*2+1] = (uint32_t)(bb >> 32);
    }
  }
  __syncthreads();

  // ---- stage 5: fc2 + bn + log_softmax (wave 0, 16 lanes) ----
  if (t < 16) {
    float vv = -1e30f;
    if (t < 10) {
      int mm = 0;
      #pragma unroll
      for (int wi = 0; wi < 8; ++wi)
        mm += __popc(h4[wi] ^ wsu[FW2P + wi*10 + t]);
      const int dot = 252 - 2*mm;
      const float B = __uint_as_float(wsu[CFP + 54 + t]);
      const float S = __uint_as_float(wsu[CFP + 64 + t]);
      const float T = __uint_as_float(wsu[CFP + 74 + t]);
      float v = __fadd_rn((float)dot, B);
      v = __fmul_rn(v, S);
      vv = __fadd_rn(v, T);
    }
    float mx = vv;
    #pragma unroll
    for (int d = 1; d < 16; d <<= 1)
      mx = fmaxf(mx, __shfl_xor(mx, d, 16));
    const float sh = __fsub_rn(vv, mx);
    float s = expf(sh);
    #pragma unroll
    for (int d = 1; d < 16; d <<= 1)
      s = __fadd_rn(s, __shfl_xor(s, d, 16));
    if (t < 10)
      out[(size_t)img*10 + t] = __fsub_rn(sh, logf(s));
  }
}

extern "C" void kernel_launch(void* const* d_in, const int* in_sizes, int n_in,
                              void* d_out, int out_size, void* d_ws, size_t ws_size,
                              hipStream_t stream)
{
  const float* x   = (const float*)d_in[0];
  const float* w1  = (const float*)d_in[1];
  const float* cb1 = (const float*)d_in[2];
  const float* g1  = (const float*)d_in[3];
  const float* be1 = (const float*)d_in[4];
  const float* m1  = (const float*)d_in[5];
  const float* v1  = (const float*)d_in[6];
  const float* w2  = (const float*)d_in[7];
  const float* cb2 = (const float*)d_in[8];
  const float* g2  = (const float*)d_in[9];
  const float* be2 = (const float*)d_in[10];
  const float* m2  = (const float*)d_in[11];
  const float* v2  = (const float*)d_in[12];
  const float* w3  = (const float*)d_in[13];
  const float* cb3 = (const float*)d_in[14];
  const float* g3  = (const float*)d_in[15];
  const float* be3 = (const float*)d_in[16];
  const float* m3  = (const float*)d_in[17];
  const float* v3  = (const float*)d_in[18];
  const float* fw1 = (const float*)d_in[19];
  const float* fb1 = (const float*)d_in[20];
  const float* g4  = (const float*)d_in[21];
  const float* be4 = (const float*)d_in[22];
  const float* m4  = (const float*)d_in[23];
  const float* v4  = (const float*)d_in[24];
  const float* fw2 = (const float*)d_in[25];
  const float* fb2 = (const float*)d_in[26];
  const float* g5  = (const float*)d_in[27];
  const float* be5 = (const float*)d_in[28];
  const float* m5  = (const float*)d_in[29];
  const float* v5  = (const float*)d_in[30];

  uint32_t* wsu = (uint32_t*)d_ws;
  float* out = (float*)d_out;

  hipLaunchKernelGGL(pack_kernel, dim3(30), dim3(256), 0, stream,
                     w1, w2, w3, fw1, fw2,
                     cb1, g1, be1, m1, v1,
                     cb2, g2, be2, m2, v2,
                     cb3, g3, be3, m3, v3,
                     fb1, g4, be4, m4, v4,
                     fb2, g5, be5, m5, v5,
                     wsu);

  hipLaunchKernelGGL(lenet_main, dim3(4096), dim3(256), 0, stream,
                     x, wsu, out);
}

// Round 6
// 49.432 us; speedup vs baseline: 1.7311x; 1.1672x over previous
//
#include <hip/hip_runtime.h>
#include <stdint.h>

typedef int v4i  __attribute__((ext_vector_type(4)));
typedef int v16i __attribute__((ext_vector_type(16)));

// ---------------- ws layout (u32 indices) ----------------
#define W1P   0      // 18  per channel: wt25 | M<<25
#define INV1  18     // 1
#define CFP   20     // 84 floats: B1[18] S1[18] T1[18] B5[10] S5[10] T5[10]
#define THRW  104    // 48 ints: D = 450-2*M2  (stage-2 dot-space threshold)
#define INVM  152    // 2 words: inv mask ch0..31, ch32..47
#define B2I   160    // 9792: i8 B^T [48][816B], k = tap*32 + c (c<18 real, else 0)
#define W3P   9952   // 120 o x 40 words (25 full + 13 hi16-pairs + 2 pad)
#define M3P   14752  // 120  M | inv<<11
#define FW1P  14872  // 252 o x 4 words
#define M4P   15880  // 252  M | inv<<7
#define FW2P  16132  // 80
// total 16212 words

__device__ inline bool negv(int dot, float B, float S, float T) {
  float v = __fadd_rn((float)dot, B);
  v = __fmul_rn(v, S);
  v = __fadd_rn(v, T);
  return v < 0.0f;
}

// neg-set over m (mismatch, dot = tot-2m) is affine-monotone: neg(m) == ((m >= M) ^ inv)
__device__ inline void scanMT(float B, float S, float T, int tot, int& M, int& inv) {
  bool b0 = negv(tot, B, S, T);
  bool be = negv(-tot, B, S, T);
  if (b0 == be) { M = 0; inv = b0 ? 0 : 1; return; }
  int lo = 0, hi = tot;
  while (hi - lo > 1) {
    int mid = (lo + hi) >> 1;
    if (negv(tot - 2*mid, B, S, T) == b0) lo = mid; else hi = mid;
  }
  M = hi; inv = b0 ? 1 : 0;
}

__device__ inline float bnS(float g, float v) {
  return __fdiv_rn(g, __fsqrt_rn(__fadd_rn(v, 1e-5f)));
}
__device__ inline float bnT(float be, float m, float s) {
  return __fsub_rn(be, __fmul_rn(m, s));
}

__global__ __launch_bounds__(256) void pack_kernel(
    const float* __restrict__ w1, const float* __restrict__ w2, const float* __restrict__ w3,
    const float* __restrict__ fw1, const float* __restrict__ fw2,
    const float* __restrict__ cb1, const float* __restrict__ g1, const float* __restrict__ be1,
    const float* __restrict__ m1, const float* __restrict__ v1,
    const float* __restrict__ cb2, const float* __restrict__ g2, const float* __restrict__ be2,
    const float* __restrict__ m2, const float* __restrict__ v2,
    const float* __restrict__ cb3, const float* __restrict__ g3, const float* __restrict__ be3,
    const float* __restrict__ m3, const float* __restrict__ v3,
    const float* __restrict__ fb1, const float* __restrict__ g4, const float* __restrict__ be4,
    const float* __restrict__ m4, const float* __restrict__ v4,
    const float* __restrict__ fb2, const float* __restrict__ g5, const float* __restrict__ be5,
    const float* __restrict__ m5, const float* __restrict__ v5,
    uint32_t* __restrict__ wsu)
{
  const int tid = blockIdx.x * 256 + threadIdx.x;

  if (tid < 18) {                         // w1 packed 25-bit + M
    int c = tid;
    uint32_t wt = 0;
    for (int ky = 0; ky < 5; ++ky)
      for (int kx = 0; kx < 5; ++kx)
        if (w1[c*25 + ky*5 + kx] < 0.0f) wt |= 1u << (ky*5 + kx);
    float S = bnS(g1[c], v1[c]);
    float B = cb1[c];
    float T = bnT(be1[c], m1[c], S);
    int M, iv; scanMT(B, S, T, 25, M, iv);
    wsu[W1P + c] = wt | ((uint32_t)M << 25);
  } else if (tid == 18) {                 // inv mask for stage1
    uint32_t mask = 0;
    for (int c = 0; c < 18; ++c) {
      float S = bnS(g1[c], v1[c]);
      float B = cb1[c];
      float T = bnT(be1[c], m1[c], S);
      int M, iv; scanMT(B, S, T, 25, M, iv);
      if (iv) mask |= 1u << c;
    }
    wsu[INV1] = mask;
  } else if (tid >= 20 && tid < 104) {    // CF floats
    int j = tid - 20;
    float outv;
    if (j < 18) outv = cb1[j];
    else if (j < 36) { int c = j - 18; outv = bnS(g1[c], v1[c]); }
    else if (j < 54) { int c = j - 36; float s = bnS(g1[c], v1[c]); outv = bnT(be1[c], m1[c], s); }
    else if (j < 64) { int c = j - 54; outv = fb2[c]; }
    else if (j < 74) { int c = j - 64; outv = bnS(g5[c], v5[c]); }
    else             { int c = j - 74; float s = bnS(g5[c], v5[c]); outv = bnT(be5[c], m5[c], s); }
    wsu[CFP + j] = __float_as_uint(outv);
  } else if (tid >= 128 && tid < 192) {   // stage-2 thresholds (one full wave: ballot)
    int o = tid - 128;
    bool inv = false;
    if (o < 48) {
      float S = bnS(g2[o], v2[o]);
      float B = cb2[o];
      float T = bnT(be2[o], m2[o], S);
      int M, iv; scanMT(B, S, T, 450, M, iv);
      wsu[THRW + o] = (uint32_t)(450 - 2*M);
      inv = (iv != 0);
    }
    unsigned long long bb = __ballot(inv);
    if (o == 0) {
      wsu[INVM]     = (uint32_t)bb;
      wsu[INVM + 1] = (uint32_t)(bb >> 32) & 0xFFFFu;
    }
  } else if (tid >= 256 && tid < 10048) { // B2I: i8 B^T [48][816]
    int idx = tid - 256;
    int o = idx / 204, rem = idx - o*204;
    int k4 = rem * 4;
    uint32_t d = 0;
    if (k4 < 800) {
      int tap = k4 >> 5, cb = k4 & 31;
      #pragma unroll
      for (int j = 0; j < 4; ++j) {
        int c = cb + j;
        uint32_t byte = 0;
        if (c < 18) byte = (w2[(o*18 + c)*25 + tap] < 0.0f) ? 0xFFu : 0x01u;
        d |= byte << (8*j);
      }
    }
    wsu[B2I + idx] = d;
  } else if (tid >= 10048 && tid < 14848) { // W3 packed [120][40]
    int idx = tid - 10048;
    int o = idx / 40, wj = idx - o*40;
    uint32_t b = 0;
    if (wj < 25) {
      int p = wj;
      for (int c = 0; c < 32; ++c)
        if (w3[(o*48 + c)*25 + p] < 0.0f) b |= 1u << c;
    } else if (wj < 38) {
      int j = wj - 25;
      int p0 = 2*j, p1 = 2*j + 1;
      for (int q = 0; q < 16; ++q) {
        int c = 32 + q;
        if (w3[(o*48 + c)*25 + p0] < 0.0f) b |= 1u << q;
        if (p1 < 25 && w3[(o*48 + c)*25 + p1] < 0.0f) b |= 1u << (16 + q);
      }
    }
    wsu[W3P + idx] = b;
  } else if (tid >= 14848 && tid < 14968) { // M3
    int o = tid - 14848;
    float S = bnS(g3[o], v3[o]);
    float B = cb3[o];
    float T = bnT(be3[o], m3[o], S);
    int M, iv; scanMT(B, S, T, 1200, M, iv);
    wsu[M3P + o] = (uint32_t)M | ((uint32_t)iv << 11);
  } else if (tid >= 15104 && tid < 16112) { // fw1 [o][4]
    int idx = tid - 15104;
    int o = idx >> 2, wi = idx & 3;
    uint32_t b = 0;
    for (int j = 0; j < 32; ++j) {
      int col = wi*32 + j;
      if (col < 120 && fw1[o*120 + col] < 0.0f) b |= 1u << j;
    }
    wsu[FW1P + idx] = b;
  } else if (tid >= 16128 && tid < 16380) { // M4
    int o = tid - 16128;
    float S = bnS(g4[o], v4[o]);
    float B = fb1[o];
    float T = bnT(be4[o], m4[o], S);
    int M, iv; scanMT(B, S, T, 120, M, iv);
    wsu[M4P + o] = (uint32_t)M | ((uint32_t)iv << 7);
  } else if (tid >= 16384 && tid < 16464) { // fw2 [wi*10+o]
    int i = tid - 16384;
    int wi = i / 10, o = i - wi*10;
    uint32_t b = 0;
    for (int j = 0; j < 32; ++j) {
      int col = wi*32 + j;
      if (col < 252 && fw2[o*252 + col] < 0.0f) b |= 1u << j;
    }
    wsu[FW2P + i] = b;
  }
}

__global__ __launch_bounds__(256) void lenet_main(
    const float* __restrict__ x, const uint32_t* __restrict__ wsu,
    float* __restrict__ out)
{
  __shared__ __align__(16) uint8_t Alds[196*32];   // i8 act [14][14][32], half-swizzled
  __shared__ __align__(16) uint8_t Blds[48*816];   // i8 B^T
  __shared__ uint32_t xng[32], xnz[32];
  __shared__ __align__(16) uint32_t h2p[40];
  __shared__ int      sthr[64];
  __shared__ uint32_t lut[16];
  __shared__ uint32_t h3[4];
  __shared__ uint32_t h4[8];
  __shared__ int      zflag;

  const int t = threadIdx.x;
  const int lane = t & 63, wid = t >> 6;
  const int img = blockIdx.x;

  // ---- staging ----
  if (t < 16) {
    uint32_t v = 0;
    #pragma unroll
    for (int b = 0; b < 4; ++b) v |= (((t >> b) & 1) ? 0xFFu : 0x01u) << (8*b);
    lut[t] = v;
  }
  if (t < 40) h2p[t] = 0;
  if (t < 64) sthr[t] = (t < 48) ? (int)wsu[THRW + t] : 0;
  if (t == 64) zflag = 0;
  {
    const uint4* bsrc = (const uint4*)(wsu + B2I);
    uint4* bdst = (uint4*)Blds;
    #pragma unroll
    for (int i = 0; i < 10; ++i) {
      int idx = t + i*256;
      if (idx < 2448) bdst[idx] = bsrc[idx];
    }
  }

  // ---- input pack: thread -> (row = t>>3, quad k = t&7) ----
  {
    const float* xim = x + (size_t)img * 1024;
    const int row = t >> 3, k = t & 7;
    const float4 f = ((const float4*)(xim + row*32))[k];
    const uint32_t u0 = __float_as_uint(f.x), u1 = __float_as_uint(f.y),
                   u2 = __float_as_uint(f.z), u3 = __float_as_uint(f.w);
    uint32_t ng = (u0>>31) | ((u1>>31)<<1) | ((u2>>31)<<2) | ((u3>>31)<<3);
    uint32_t nz = (uint32_t)((u0<<1)!=0u) | ((uint32_t)((u1<<1)!=0u)<<1)
                | ((uint32_t)((u2<<1)!=0u)<<2) | ((uint32_t)((u3<<1)!=0u)<<3);
    ng <<= 4*k; nz <<= 4*k;
    ng |= __shfl_xor(ng, 1);  nz |= __shfl_xor(nz, 1);
    ng |= __shfl_xor(ng, 2);  nz |= __shfl_xor(nz, 2);
    ng |= __shfl_xor(ng, 4);  nz |= __shfl_xor(nz, 4);
    if (k == 0) {
      xng[row] = ng;
      xnz[row] = nz;
      if (nz != 0xFFFFFFFFu) atomicOr(&zflag, 1);
    }
  }
  __syncthreads();

  // ---- stage 1: conv1 + pool + threshold, then expand to i8 A in LDS ----
  const bool zer = (zflag != 0);
  if (t < 196) {
    const int py = t / 14, px = t - py*14;
    const int x0 = 2*px, y0 = 2*py;
    uint32_t hm = 0;
    if (!zer) {
      const uint32_t a0 = xng[y0+0] >> x0, a1 = xng[y0+1] >> x0,
                     a2 = xng[y0+2] >> x0, a3 = xng[y0+3] >> x0,
                     a4 = xng[y0+4] >> x0, a5 = xng[y0+5] >> x0;
      const uint32_t w00 = (a0&31u) | ((a1&31u)<<5) | ((a2&31u)<<10) | ((a3&31u)<<15) | ((a4&31u)<<20);
      const uint32_t w01 = ((a0>>1)&31u) | (((a1>>1)&31u)<<5) | (((a2>>1)&31u)<<10) | (((a3>>1)&31u)<<15) | (((a4>>1)&31u)<<20);
      const uint32_t w10 = (a1&31u) | ((a2&31u)<<5) | ((a3&31u)<<10) | ((a4&31u)<<15) | ((a5&31u)<<20);
      const uint32_t w11 = ((a1>>1)&31u) | (((a2>>1)&31u)<<5) | (((a3>>1)&31u)<<10) | (((a4>>1)&31u)<<15) | (((a5>>1)&31u)<<20);
      const uint32_t iv1 = wsu[INV1];
      #pragma unroll
      for (int c = 0; c < 18; ++c) {
        const uint32_t wd = wsu[W1P + c];
        const uint32_t wt = wd & 0x1FFFFFFu;
        const int M = (int)(wd >> 25);
        const int mn = min(min(__popc(w00^wt), __popc(w01^wt)),
                           min(__popc(w10^wt), __popc(w11^wt)));
        hm |= (mn >= M) ? (1u << c) : 0u;
      }
      hm ^= iv1;
    } else {                              // exact-zero-aware float path (rare)
      uint32_t an[6], az[6];
      #pragma unroll
      for (int r6 = 0; r6 < 6; ++r6) { an[r6] = xng[y0+r6] >> x0; az[r6] = xnz[y0+r6] >> x0; }
      for (int c = 0; c < 18; ++c) {
        const uint32_t wt = wsu[W1P + c] & 0x1FFFFFFu;
        const float B = __uint_as_float(wsu[CFP + c]);
        const float S = __uint_as_float(wsu[CFP + 18 + c]);
        const float T = __uint_as_float(wsu[CFP + 36 + c]);
        int best = -1000;
        #pragma unroll
        for (int dy = 0; dy < 2; ++dy)
          #pragma unroll
          for (int dx = 0; dx < 2; ++dx) {
            int cnt = 0, ng = 0;
            #pragma unroll
            for (int k = 0; k < 5; ++k) {
              const uint32_t nzr = (az[dy+k] >> dx) & 31u;
              const uint32_t sgr = (an[dy+k] >> dx) & 31u;
              const uint32_t wr  = (wt >> (5*k)) & 31u;
              cnt += __popc(nzr);
              ng  += __popc((sgr ^ wr) & nzr);
            }
            const int conv = cnt - 2*ng;
            best = best > conv ? best : conv;
          }
        if (negv(best, B, S, T)) hm |= 1u << c;
      }
    }
    // expand 18 bits -> 32 i8 (c>=18 zero), halves swapped by pixel parity
    const uint32_t d0 = lut[hm & 15u];
    const uint32_t d1 = lut[(hm >> 4) & 15u];
    const uint32_t d2 = lut[(hm >> 8) & 15u];
    const uint32_t d3 = lut[(hm >> 12) & 15u];
    const uint32_t d4 = lut[(hm >> 16) & 15u] & 0x0000FFFFu;
    const int swz = (t & 1) << 4;
    uint8_t* ap = Alds + t*32;
    *(uint2*)(ap + swz)            = make_uint2(d0, d1);
    *(uint2*)(ap + swz + 8)        = make_uint2(d2, d3);
    *(uint2*)(ap + (swz ^ 16))     = make_uint2(d4, 0u);
    *(uint2*)(ap + (swz ^ 16) + 8) = make_uint2(0u, 0u);
  }
  __syncthreads();

  // ---- stage 2: conv2 as i8 MFMA (M=128 pool-major, N=64, K=800) ----
  {
    const int rl = lane & 31, kh = lane >> 5;
    const int q   = (wid << 3) + (rl >> 2);    // pool (garbage >=25 ok)
    const int wnd = rl & 3;
    const int py = q / 5, px = q - py*5;
    const int Y = 2*py + (wnd >> 1), X = 2*px + (wnd & 1);
    const uint32_t pbase = (uint32_t)((Y*14 + X) * 32);
    const uint32_t aeven = pbase + (uint32_t)(((kh ^ (X & 1)) & 1) << 4);
    const uint32_t aodd  = aeven ^ 16u;
    const int oc0 = rl;
    const int oc1 = min(rl + 32, 47);
    const uint32_t bb0 = (uint32_t)(oc0*816 + (kh << 4));
    const uint32_t bb1 = (uint32_t)(oc1*816 + (kh << 4));

    v16i acc0 = {};
    v16i acc1 = {};
    #pragma unroll
    for (int ks = 0; ks < 25; ++ks) {
      const int ky = ks / 5, kx = ks - (ks/5)*5;
      const uint32_t aoff = (uint32_t)((ky*14 + kx) * 32);
      v4i a  = *(const v4i*)(Alds + ((kx & 1) ? aodd : aeven) + aoff);
      v4i b0 = *(const v4i*)(Blds + bb0 + ks*32);
      v4i b1 = *(const v4i*)(Blds + bb1 + ks*32);
      acc0 = __builtin_amdgcn_mfma_i32_32x32x32_i8(a, b0, acc0, 0, 0, 0);
      acc1 = __builtin_amdgcn_mfma_i32_32x32x32_i8(a, b1, acc1, 0, 0, 0);
    }

    const int D0 = sthr[oc0];
    const int D1 = sthr[oc1];
    const uint32_t ivm0 = wsu[INVM];
    const uint32_t ivm1d = (wsu[INVM + 1] & 0xFFFFu) * 0x10001u;
    #pragma unroll
    for (int g = 0; g < 4; ++g) {
      const int p0 = max(max(acc0[4*g], acc0[4*g+1]), max(acc0[4*g+2], acc0[4*g+3]));
      const int p1 = max(max(acc1[4*g], acc1[4*g+1]), max(acc1[4*g+2], acc1[4*g+3]));
      unsigned long long e0 = __ballot(p0 <= D0);
      unsigned long long e1 = __ballot(p1 <= D1);
      if (lane == 0) {
        const int pool = (wid << 3) + 2*g;
        if (pool < 25) {
          h2p[pool] = (uint32_t)e0 ^ ivm0;
          uint32_t hw = ((uint32_t)e1 & 0xFFFFu) | (((uint32_t)(e1 >> 32) & 0xFFFFu) << 16);
          hw ^= ivm1d;
          if (pool + 1 < 25) h2p[pool + 1] = (uint32_t)(e0 >> 32) ^ ivm0;
          else hw &= 0xFFFFu;
          h2p[25 + (pool >> 1)] = hw;
        }
      }
    }
  }
  __syncthreads();

  // ---- stage 3: conv3 (48->120), 240 thr = (o, half of 40 words) ----
  {
    bool pred = false;
    if (t < 240) {
      const int o = t >> 1, h = t & 1;
      const uint4* wp = (const uint4*)(wsu + W3P + o*40 + h*20);
      const uint32_t* hv = &h2p[h*20];
      int mm = 0;
      #pragma unroll
      for (int qq = 0; qq < 5; ++qq) {
        const uint4 ww = wp[qq];
        mm += __popc(hv[qq*4+0] ^ ww.x) + __popc(hv[qq*4+1] ^ ww.y)
            + __popc(hv[qq*4+2] ^ ww.z) + __popc(hv[qq*4+3] ^ ww.w);
      }
      mm += __shfl_xor(mm, 1);
      const uint32_t mw = wsu[M3P + o];
      pred = (((mm >= (int)(mw & 2047u)) ? 1u : 0u) ^ (mw >> 11)) != 0u;
    }
    unsigned long long bb = __ballot(pred && ((t & 1) == 0));
    unsigned long long xq = bb & 0x5555555555555555ull;
    xq = (xq | (xq >> 1))  & 0x3333333333333333ull;
    xq = (xq | (xq >> 2))  & 0x0F0F0F0F0F0F0F0Full;
    xq = (xq | (xq >> 4))  & 0x00FF00FF00FF00FFull;
    xq = (xq | (xq >> 8))  & 0x0000FFFF0000FFFFull;
    xq = (xq | (xq >> 16)) & 0x00000000FFFFFFFFull;
    if (lane == 0) h3[wid] = (uint32_t)xq;
  }
  __syncthreads();

  // ---- stage 4: fc1 (120->252), ballot -> h4 ----
  {
    bool pred = false;
    if (t < 252) {
      const uint4 fr = ((const uint4*)(wsu + FW1P))[t];
      const int mm = __popc(h3[0] ^ fr.x) + __popc(h3[1] ^ fr.y)
                   + __popc(h3[2] ^ fr.z) + __popc(h3[3] ^ fr.w);
      const uint32_t mw = wsu[M4P + t];
      pred = (((mm >= (int)(mw & 127u)) ? 1u : 0u) ^ (mw >> 7)) != 0u;
    }
    unsigned long long bb = __ballot(pred);
    if (lane == 0) {
      h4[wid*2]   = (uint32_t)bb;
      h4[wid*2+1] = (uint32_t)(bb >> 32);
    }
  }
  __syncthreads();

  // ---- stage 5: fc2 + bn + log_softmax ----
  if (t < 16) {
    float vv = -1e30f;
    if (t < 10) {
      int mm = 0;
      #pragma unroll
      for (int wi = 0; wi < 8; ++wi)
        mm += __popc(h4[wi] ^ wsu[FW2P + wi*10 + t]);
      const int dot = 252 - 2*mm;
      const float B = __uint_as_float(wsu[CFP + 54 + t]);
      const float S = __uint_as_float(wsu[CFP + 64 + t]);
      const float T = __uint_as_float(wsu[CFP + 74 + t]);
      float v = __fadd_rn((float)dot, B);
      v = __fmul_rn(v, S);
      vv = __fadd_rn(v, T);
    }
    float mx = vv;
    #pragma unroll
    for (int d = 1; d < 16; d <<= 1)
      mx = fmaxf(mx, __shfl_xor(mx, d, 16));
    const float sh = __fsub_rn(vv, mx);
    float s = expf(sh);
    #pragma unroll
    for (int d = 1; d < 16; d <<= 1)
      s = __fadd_rn(s, __shfl_xor(s, d, 16));
    if (t < 10)
      out[(size_t)img*10 + t] = __fsub_rn(sh, logf(s));
  }
}

extern "C" void kernel_launch(void* const* d_in, const int* in_sizes, int n_in,
                              void* d_out, int out_size, void* d_ws, size_t ws_size,
                              hipStream_t stream)
{
  const float* x   = (const float*)d_in[0];
  const float* w1  = (const float*)d_in[1];
  const float* cb1 = (const float*)d_in[2];
  const float* g1  = (const float*)d_in[3];
  const float* be1 = (const float*)d_in[4];
  const float* m1  = (const float*)d_in[5];
  const float* v1  = (const float*)d_in[6];
  const float* w2  = (const float*)d_in[7];
  const float* cb2 = (const float*)d_in[8];
  const float* g2  = (const float*)d_in[9];
  const float* be2 = (const float*)d_in[10];
  const float* m2  = (const float*)d_in[11];
  const float* v2  = (const float*)d_in[12];
  const float* w3  = (const float*)d_in[13];
  const float* cb3 = (const float*)d_in[14];
  const float* g3  = (const float*)d_in[15];
  const float* be3 = (const float*)d_in[16];
  const float* m3  = (const float*)d_in[17];
  const float* v3  = (const float*)d_in[18];
  const float* fw1 = (const float*)d_in[19];
  const float* fb1 = (const float*)d_in[20];
  const float* g4  = (const float*)d_in[21];
  const float* be4 = (const float*)d_in[22];
  const float* m4  = (const float*)d_in[23];
  const float* v4  = (const float*)d_in[24];
  const float* fw2 = (const float*)d_in[25];
  const float* fb2 = (const float*)d_in[26];
  const float* g5  = (const float*)d_in[27];
  const float* be5 = (const float*)d_in[28];
  const float* m5  = (const float*)d_in[29];
  const float* v5  = (const float*)d_in[30];

  uint32_t* wsu = (uint32_t*)d_ws;
  float* out = (float*)d_out;

  hipLaunchKernelGGL(pack_kernel, dim3(65), dim3(256), 0, stream,
                     w1, w2, w3, fw1, fw2,
                     cb1, g1, be1, m1, v1,
                     cb2, g2, be2, m2, v2,
                     cb3, g3, be3, m3, v3,
                     fb1, g4, be4, m4, v4,
                     fb2, g5, be5, m5, v5,
                     wsu);

  hipLaunchKernelGGL(lenet_main, dim3(4096), dim3(256), 0, stream,
                     x, wsu, out);
}